// Round 1
// baseline (596.037 us; speedup 1.0000x reference)
//
#include <hip/hip_runtime.h>
#include <hip/hip_bf16.h>
#include <math.h>

#define N_NODES_C 50000
#define IN_DIM 128
#define HID 64
#define NREL 2

// ---------------------------------------------------------------------------
// Utility: zero an int array
// ---------------------------------------------------------------------------
__global__ void zero_ints(int* p, int n) {
    int i = blockIdx.x * blockDim.x + threadIdx.x;
    if (i < n) p[i] = 0;
}

// ---------------------------------------------------------------------------
// CSR build: count edges per (rel, dst)
// ---------------------------------------------------------------------------
__global__ void count_edges(const int* __restrict__ et, const int* __restrict__ dst,
                            int* __restrict__ cnt, int E, int N) {
    int e = blockIdx.x * blockDim.x + threadIdx.x;
    if (e < E) {
        atomicAdd(&cnt[et[e] * N + dst[e]], 1);
    }
}

// ---------------------------------------------------------------------------
// Scan phase 1: per-block (1024 elems) exclusive scan + block sums
// ---------------------------------------------------------------------------
#define SCAN_T 256
#define SCAN_I 4
__global__ void scan_phase1(const int* __restrict__ in, int* __restrict__ excl,
                            int* __restrict__ bsum, int n) {
    __shared__ int sdata[SCAN_T];
    int b = blockIdx.x;
    int t = threadIdx.x;
    int base = b * SCAN_T * SCAN_I;
    int v[SCAN_I];
    int s = 0;
#pragma unroll
    for (int i = 0; i < SCAN_I; ++i) {
        int idx = base + t * SCAN_I + i;
        v[i] = (idx < n) ? in[idx] : 0;
        s += v[i];
    }
    sdata[t] = s;
    __syncthreads();
    // inclusive Hillis-Steele over 256
    for (int off = 1; off < SCAN_T; off <<= 1) {
        int x = (t >= off) ? sdata[t - off] : 0;
        __syncthreads();
        sdata[t] += x;
        __syncthreads();
    }
    int run = sdata[t] - s;  // exclusive prefix of this thread's chunk
    if (bsum && t == SCAN_T - 1) bsum[b] = sdata[SCAN_T - 1];
#pragma unroll
    for (int i = 0; i < SCAN_I; ++i) {
        int idx = base + t * SCAN_I + i;
        if (idx < n) excl[idx] = run;
        run += v[i];
    }
}

// ---------------------------------------------------------------------------
// Scan phase 3: add block offsets, produce rowptr and cursor copies
// ---------------------------------------------------------------------------
__global__ void scan_phase3(const int* __restrict__ excl, const int* __restrict__ boff,
                            int* __restrict__ rowptr, int* __restrict__ cursor,
                            int n, int total) {
    int i = blockIdx.x * blockDim.x + threadIdx.x;
    if (i < n) {
        int v = excl[i] + boff[i / (SCAN_T * SCAN_I)];
        rowptr[i] = v;
        cursor[i] = v;
    }
    if (i == 0) rowptr[n] = total;
}

// ---------------------------------------------------------------------------
// CSR fill: scatter src indices into relation/dst-grouped slots
// ---------------------------------------------------------------------------
__global__ void fill_edges(const int* __restrict__ et, const int* __restrict__ src,
                           const int* __restrict__ dst, int* __restrict__ cursor,
                           int* __restrict__ col, int E, int N) {
    int e = blockIdx.x * blockDim.x + threadIdx.x;
    if (e < E) {
        int slot = atomicAdd(&cursor[et[e] * N + dst[e]], 1);
        col[slot] = src[e];
    }
}

// ---------------------------------------------------------------------------
// Packed GEMM: [M,K] @ ([K,64]|[K,64]|[K,64]) -> PA, PB, PR   (fp32 vector)
// Block: 256 threads, 64 rows per block, full 192 cols, K chunked by 16.
// Each wave (4 per block) owns 16 rows; lane owns cols {lane, lane+64, lane+128}.
// ---------------------------------------------------------------------------
#define TM 64
#define KC 16
template <int K>
__global__ __launch_bounds__(256) void gemm_pack(
    const float* __restrict__ X,
    const float* __restrict__ Wa, const float* __restrict__ Wb,
    const float* __restrict__ Wr,
    float* __restrict__ PA, float* __restrict__ PB, float* __restrict__ PR,
    int M) {
    __shared__ float xs[TM][KC];     // 4 KB
    __shared__ float ws[KC][192];    // 12 KB
    const int t = threadIdx.x;
    const int lane = t & 63;
    const int w = t >> 6;
    const int r0 = w * 16;
    const int row0 = blockIdx.x * TM;

    float acc[16][3];
#pragma unroll
    for (int r = 0; r < 16; ++r) { acc[r][0] = 0.f; acc[r][1] = 0.f; acc[r][2] = 0.f; }

    for (int k0 = 0; k0 < K; k0 += KC) {
        // stage x tile: 64 rows x 16 k
        {
            int r = t >> 2;
            int kq = t & 3;
            int grow = row0 + r;
            float4 v = make_float4(0.f, 0.f, 0.f, 0.f);
            if (grow < M)
                v = *reinterpret_cast<const float4*>(X + (size_t)grow * K + k0 + kq * 4);
            *reinterpret_cast<float4*>(&xs[r][kq * 4]) = v;
        }
        // stage W tile: 16 k x 192 cols, from the three packed sources
#pragma unroll
        for (int i = 0; i < 12; ++i) {
            int idx = t + i * 256;
            int kk = idx / 192;
            int j = idx - kk * 192;
            const float* sp = (j < 64) ? (Wa + (size_t)(k0 + kk) * 64 + j)
                              : (j < 128) ? (Wb + (size_t)(k0 + kk) * 64 + (j - 64))
                                          : (Wr + (size_t)(k0 + kk) * 64 + (j - 128));
            ws[kk][j] = *sp;
        }
        __syncthreads();

#pragma unroll
        for (int kq = 0; kq < KC / 4; ++kq) {
            float wv[4][3];
#pragma unroll
            for (int kk = 0; kk < 4; ++kk) {
                wv[kk][0] = ws[kq * 4 + kk][lane];
                wv[kk][1] = ws[kq * 4 + kk][lane + 64];
                wv[kk][2] = ws[kq * 4 + kk][lane + 128];
            }
#pragma unroll
            for (int r = 0; r < 16; ++r) {
                float4 xv = *reinterpret_cast<const float4*>(&xs[r0 + r][kq * 4]);
                acc[r][0] = fmaf(xv.x, wv[0][0], acc[r][0]);
                acc[r][1] = fmaf(xv.x, wv[0][1], acc[r][1]);
                acc[r][2] = fmaf(xv.x, wv[0][2], acc[r][2]);
                acc[r][0] = fmaf(xv.y, wv[1][0], acc[r][0]);
                acc[r][1] = fmaf(xv.y, wv[1][1], acc[r][1]);
                acc[r][2] = fmaf(xv.y, wv[1][2], acc[r][2]);
                acc[r][0] = fmaf(xv.z, wv[2][0], acc[r][0]);
                acc[r][1] = fmaf(xv.z, wv[2][1], acc[r][1]);
                acc[r][2] = fmaf(xv.z, wv[2][2], acc[r][2]);
                acc[r][0] = fmaf(xv.w, wv[3][0], acc[r][0]);
                acc[r][1] = fmaf(xv.w, wv[3][1], acc[r][1]);
                acc[r][2] = fmaf(xv.w, wv[3][2], acc[r][2]);
            }
        }
        __syncthreads();
    }

#pragma unroll
    for (int r = 0; r < 16; ++r) {
        int grow = row0 + r0 + r;
        if (grow < M) {
            PA[(size_t)grow * 64 + lane] = acc[r][0];
            PB[(size_t)grow * 64 + lane] = acc[r][1];
            PR[(size_t)grow * 64 + lane] = acc[r][2];
        }
    }
}

// ---------------------------------------------------------------------------
// Aggregate + LayerNorm (+ optional exact GELU).
// One wave per node; lane = feature channel (64 channels).
// ---------------------------------------------------------------------------
__global__ __launch_bounds__(256) void agg_ln_kernel(
    const float* __restrict__ PA, const float* __restrict__ PB,
    const float* __restrict__ PR,
    const int* __restrict__ rowptr, const int* __restrict__ col,
    const float* __restrict__ bias, const float* __restrict__ g,
    const float* __restrict__ beta,
    float* __restrict__ out, int N, int gelu) {
    int t = threadIdx.x;
    int lane = t & 63;
    int node = blockIdx.x * 4 + (t >> 6);
    if (node >= N) return;

    float acc = PR[(size_t)node * 64 + lane] + bias[lane];

#pragma unroll
    for (int r = 0; r < 2; ++r) {
        const float* __restrict__ P = r ? PB : PA;
        int beg = rowptr[r * N + node];
        int end = rowptr[r * N + node + 1];
        float s = 0.f;
        for (int e = beg; e < end; ++e) {
            s += P[(size_t)col[e] * 64 + lane];
        }
        int deg = end - beg;
        if (deg > 0) acc += s / (float)deg;
    }

    // LayerNorm over the 64 lanes
    float m = acc;
#pragma unroll
    for (int off = 32; off > 0; off >>= 1) m += __shfl_xor(m, off);
    m *= (1.f / 64.f);
    float d = acc - m;
    float v = d * d;
#pragma unroll
    for (int off = 32; off > 0; off >>= 1) v += __shfl_xor(v, off);
    v *= (1.f / 64.f);
    float y = d * (1.f / sqrtf(v + 1e-5f)) * g[lane] + beta[lane];

    if (gelu) y = 0.5f * y * (1.f + erff(y * 0.70710678118654752440f));

    out[(size_t)node * 64 + lane] = y;
}

// ---------------------------------------------------------------------------
// Launch
// ---------------------------------------------------------------------------
extern "C" void kernel_launch(void* const* d_in, const int* in_sizes, int n_in,
                              void* d_out, int out_size, void* d_ws, size_t ws_size,
                              hipStream_t stream) {
    const float* x = (const float*)d_in[0];
    const int* ei = (const int*)d_in[1];   // [2][E]: src row then dst row
    const int* et = (const int*)d_in[2];   // [E]
    const float* W1 = (const float*)d_in[3];    // [2][128][64]
    const float* root1 = (const float*)d_in[4]; // [128][64]
    const float* b1 = (const float*)d_in[5];
    const float* g1 = (const float*)d_in[6];
    const float* beta1 = (const float*)d_in[7];
    const float* W2 = (const float*)d_in[8];    // [2][64][64]
    const float* root2 = (const float*)d_in[9]; // [64][64]
    const float* b2 = (const float*)d_in[10];
    const float* g2 = (const float*)d_in[11];
    const float* beta2 = (const float*)d_in[12];

    const int E = in_sizes[2];
    const int N = in_sizes[0] / IN_DIM;
    const int nseg = NREL * N;

    // workspace layout (floats then ints)
    float* PA = (float*)d_ws;
    float* PB = PA + (size_t)N * 64;
    float* PR = PB + (size_t)N * 64;
    float* H  = PR + (size_t)N * 64;
    int* cnt    = (int*)(H + (size_t)N * 64);
    int* excl   = cnt + nseg;
    int* rowptr = excl + nseg;          // nseg + 1
    int* cursor = rowptr + nseg + 1;
    int* colA   = cursor + nseg;        // E
    int* bsum   = colA + E;             // 256
    int* boff   = bsum + 256;           // 256

    const int* esrc = ei;
    const int* edst = ei + E;

    // ---- CSR build ----
    zero_ints<<<(nseg + 255) / 256, 256, 0, stream>>>(cnt, nseg);
    count_edges<<<(E + 255) / 256, 256, 0, stream>>>(et, edst, cnt, E, N);
    int nb = (nseg + SCAN_T * SCAN_I - 1) / (SCAN_T * SCAN_I);
    scan_phase1<<<nb, SCAN_T, 0, stream>>>(cnt, excl, bsum, nseg);
    scan_phase1<<<1, SCAN_T, 0, stream>>>(bsum, boff, nullptr, nb);
    scan_phase3<<<(nseg + 255) / 256, 256, 0, stream>>>(excl, boff, rowptr, cursor,
                                                        nseg, E);
    fill_edges<<<(E + 255) / 256, 256, 0, stream>>>(et, esrc, edst, cursor, colA, E, N);

    // ---- Layer 1 ----
    int gblocks = (N + TM - 1) / TM;
    gemm_pack<IN_DIM><<<gblocks, 256, 0, stream>>>(
        x, W1, W1 + (size_t)IN_DIM * 64, root1, PA, PB, PR, N);
    agg_ln_kernel<<<(N + 3) / 4, 256, 0, stream>>>(PA, PB, PR, rowptr, colA, b1, g1,
                                                   beta1, H, N, 1);

    // ---- Layer 2 ----
    gemm_pack<HID><<<gblocks, 256, 0, stream>>>(
        H, W2, W2 + (size_t)HID * 64, root2, PA, PB, PR, N);
    agg_ln_kernel<<<(N + 3) / 4, 256, 0, stream>>>(PA, PB, PR, rowptr, colA, b2, g2,
                                                   beta2, (float*)d_out, N, 0);
}

// Round 2
// 454.709 us; speedup vs baseline: 1.3108x; 1.3108x over previous
//
#include <hip/hip_runtime.h>
#include <hip/hip_bf16.h>
#include <math.h>

#define IN_DIM 128
#define HID 64
#define NREL 2

// ---------------------------------------------------------------------------
// Utility: zero an int array
// ---------------------------------------------------------------------------
__global__ void zero_ints(int* p, int n) {
    int i = blockIdx.x * blockDim.x + threadIdx.x;
    if (i < n) p[i] = 0;
}

// ---------------------------------------------------------------------------
// CSR build: count edges per (rel, dst)
// ---------------------------------------------------------------------------
__global__ void count_edges(const int* __restrict__ et, const int* __restrict__ dst,
                            int* __restrict__ cnt, int E, int N) {
    int e = blockIdx.x * blockDim.x + threadIdx.x;
    if (e < E) {
        atomicAdd(&cnt[et[e] * N + dst[e]], 1);
    }
}

// ---------------------------------------------------------------------------
// Scan phase 1: per-block (1024 elems) exclusive scan + block sums
// ---------------------------------------------------------------------------
#define SCAN_T 256
#define SCAN_I 4
__global__ void scan_phase1(const int* __restrict__ in, int* __restrict__ excl,
                            int* __restrict__ bsum, int n) {
    __shared__ int sdata[SCAN_T];
    int b = blockIdx.x;
    int t = threadIdx.x;
    int base = b * SCAN_T * SCAN_I;
    int v[SCAN_I];
    int s = 0;
#pragma unroll
    for (int i = 0; i < SCAN_I; ++i) {
        int idx = base + t * SCAN_I + i;
        v[i] = (idx < n) ? in[idx] : 0;
        s += v[i];
    }
    sdata[t] = s;
    __syncthreads();
    for (int off = 1; off < SCAN_T; off <<= 1) {
        int x = (t >= off) ? sdata[t - off] : 0;
        __syncthreads();
        sdata[t] += x;
        __syncthreads();
    }
    int run = sdata[t] - s;
    if (bsum && t == SCAN_T - 1) bsum[b] = sdata[SCAN_T - 1];
#pragma unroll
    for (int i = 0; i < SCAN_I; ++i) {
        int idx = base + t * SCAN_I + i;
        if (idx < n) excl[idx] = run;
        run += v[i];
    }
}

// ---------------------------------------------------------------------------
// Scan phase 3: add block offsets, produce rowptr and cursor copies
// ---------------------------------------------------------------------------
__global__ void scan_phase3(const int* __restrict__ excl, const int* __restrict__ boff,
                            int* __restrict__ rowptr, int* __restrict__ cursor,
                            int n, int total) {
    int i = blockIdx.x * blockDim.x + threadIdx.x;
    if (i < n) {
        int v = excl[i] + boff[i / (SCAN_T * SCAN_I)];
        rowptr[i] = v;
        cursor[i] = v;
    }
    if (i == 0) rowptr[n] = total;
}

// ---------------------------------------------------------------------------
// CSR fill: scatter src indices into relation/dst-grouped slots
// ---------------------------------------------------------------------------
__global__ void fill_edges(const int* __restrict__ et, const int* __restrict__ src,
                           const int* __restrict__ dst, int* __restrict__ cursor,
                           int* __restrict__ col, int E, int N) {
    int e = blockIdx.x * blockDim.x + threadIdx.x;
    if (e < E) {
        int slot = atomicAdd(&cursor[et[e] * N + dst[e]], 1);
        col[slot] = src[e];
    }
}

// ---------------------------------------------------------------------------
// Tall-skinny packed GEMM, no LDS, no barriers.
// [M,K] @ ([K,64]|[K,64]|[K,64]) -> PA, PB, PR   (fp32 VALU)
//
// Block 256 = 4 waves; each wave owns 16 rows (nodes). Lane l holds
// x[row][2l], x[row][2l+1] in registers (wave's rows fully register-resident)
// and owns output columns {l, l+64, l+128}. Inner loop: broadcast x[row][k]
// via v_readlane (uniform index -> SGPR operand), FMA against per-lane W
// values loaded from global (W is 48-96 KB -> L1/L2 resident). Per k:
// 16 readlane + 48 FMA. W chunks double-buffered with static indices.
// ---------------------------------------------------------------------------
__device__ __forceinline__ float bcast_lane(float v, int srclane) {
    return __int_as_float(__builtin_amdgcn_readlane(__float_as_int(v), srclane));
}

template <int K>
__global__ __launch_bounds__(256, 3) void gemm_bcast(
    const float* __restrict__ X,
    const float* __restrict__ Wa, const float* __restrict__ Wb,
    const float* __restrict__ Wr,
    float* __restrict__ PA, float* __restrict__ PB, float* __restrict__ PR,
    int M) {
    const int lane = threadIdx.x & 63;
    const int row0 = blockIdx.x * 64 + (threadIdx.x >> 6) * 16;

    // Register-resident x slice: lane l holds x[row][2l], x[row][2l+1]
    float xe[16], xo[16];
#pragma unroll
    for (int r = 0; r < 16; ++r) {
        int row = row0 + r;
        float2 v = make_float2(0.f, 0.f);
        if (row < M && 2 * lane < K)
            v = *reinterpret_cast<const float2*>(X + (size_t)row * K + 2 * lane);
        xe[r] = v.x;
        xo[r] = v.y;
    }

    float a0[16], a1[16], a2[16];
#pragma unroll
    for (int r = 0; r < 16; ++r) { a0[r] = 0.f; a1[r] = 0.f; a2[r] = 0.f; }

    float bufA[3][4], bufB[3][4];

#define LOADW(BUF, KB)                                                        \
    {                                                                         \
        _Pragma("unroll") for (int kk = 0; kk < 4; ++kk) {                    \
            BUF[0][kk] = Wa[(size_t)((KB) + kk) * 64 + lane];                 \
            BUF[1][kk] = Wb[(size_t)((KB) + kk) * 64 + lane];                 \
            BUF[2][kk] = Wr[(size_t)((KB) + kk) * 64 + lane];                 \
        }                                                                     \
    }

    // Per 4-k chunk: k = KB + {0,1,2,3}; KB % 4 == 0, so srclane for the
    // pair (2kp, 2kp+1) is (KB>>1)+kp; even k uses xe, odd uses xo.
#define COMPUTE(BUF, KB)                                                      \
    {                                                                         \
        _Pragma("unroll") for (int kp = 0; kp < 2; ++kp) {                    \
            const int sl = ((KB) >> 1) + kp;                                  \
            _Pragma("unroll") for (int r = 0; r < 16; ++r) {                  \
                float ve = bcast_lane(xe[r], sl);                             \
                a0[r] = fmaf(ve, BUF[0][2 * kp], a0[r]);                      \
                a1[r] = fmaf(ve, BUF[1][2 * kp], a1[r]);                      \
                a2[r] = fmaf(ve, BUF[2][2 * kp], a2[r]);                      \
                float vo = bcast_lane(xo[r], sl);                             \
                a0[r] = fmaf(vo, BUF[0][2 * kp + 1], a0[r]);                  \
                a1[r] = fmaf(vo, BUF[1][2 * kp + 1], a1[r]);                  \
                a2[r] = fmaf(vo, BUF[2][2 * kp + 1], a2[r]);                  \
            }                                                                 \
        }                                                                     \
    }

    LOADW(bufA, 0);
    int k0 = 0;
    for (; k0 < K - 8; k0 += 8) {
        LOADW(bufB, k0 + 4);
        COMPUTE(bufA, k0);
        LOADW(bufA, k0 + 8);
        COMPUTE(bufB, k0 + 4);
    }
    // tail: k0 == K-8
    LOADW(bufB, k0 + 4);
    COMPUTE(bufA, k0);
    COMPUTE(bufB, k0 + 4);

#undef LOADW
#undef COMPUTE

#pragma unroll
    for (int r = 0; r < 16; ++r) {
        int row = row0 + r;
        if (row < M) {
            PA[(size_t)row * 64 + lane] = a0[r];
            PB[(size_t)row * 64 + lane] = a1[r];
            PR[(size_t)row * 64 + lane] = a2[r];
        }
    }
}

// ---------------------------------------------------------------------------
// Aggregate + LayerNorm (+ optional exact GELU).
// One wave per node; lane = feature channel (64 channels).
// ---------------------------------------------------------------------------
__global__ __launch_bounds__(256) void agg_ln_kernel(
    const float* __restrict__ PA, const float* __restrict__ PB,
    const float* __restrict__ PR,
    const int* __restrict__ rowptr, const int* __restrict__ col,
    const float* __restrict__ bias, const float* __restrict__ g,
    const float* __restrict__ beta,
    float* __restrict__ out, int N, int gelu) {
    int t = threadIdx.x;
    int lane = t & 63;
    int node = blockIdx.x * 4 + (t >> 6);
    if (node >= N) return;

    float acc = PR[(size_t)node * 64 + lane] + bias[lane];

#pragma unroll
    for (int r = 0; r < 2; ++r) {
        const float* __restrict__ P = r ? PB : PA;
        int beg = rowptr[r * N + node];
        int end = rowptr[r * N + node + 1];
        float s = 0.f;
        for (int e = beg; e < end; ++e) {
            s += P[(size_t)col[e] * 64 + lane];
        }
        int deg = end - beg;
        if (deg > 0) acc += s / (float)deg;
    }

    // LayerNorm over the 64 lanes
    float m = acc;
#pragma unroll
    for (int off = 32; off > 0; off >>= 1) m += __shfl_xor(m, off);
    m *= (1.f / 64.f);
    float d = acc - m;
    float v = d * d;
#pragma unroll
    for (int off = 32; off > 0; off >>= 1) v += __shfl_xor(v, off);
    v *= (1.f / 64.f);
    float y = d * (1.f / sqrtf(v + 1e-5f)) * g[lane] + beta[lane];

    if (gelu) y = 0.5f * y * (1.f + erff(y * 0.70710678118654752440f));

    out[(size_t)node * 64 + lane] = y;
}

// ---------------------------------------------------------------------------
// Launch
// ---------------------------------------------------------------------------
extern "C" void kernel_launch(void* const* d_in, const int* in_sizes, int n_in,
                              void* d_out, int out_size, void* d_ws, size_t ws_size,
                              hipStream_t stream) {
    const float* x = (const float*)d_in[0];
    const int* ei = (const int*)d_in[1];   // [2][E]: src row then dst row
    const int* et = (const int*)d_in[2];   // [E]
    const float* W1 = (const float*)d_in[3];    // [2][128][64]
    const float* root1 = (const float*)d_in[4]; // [128][64]
    const float* b1 = (const float*)d_in[5];
    const float* g1 = (const float*)d_in[6];
    const float* beta1 = (const float*)d_in[7];
    const float* W2 = (const float*)d_in[8];    // [2][64][64]
    const float* root2 = (const float*)d_in[9]; // [64][64]
    const float* b2 = (const float*)d_in[10];
    const float* g2 = (const float*)d_in[11];
    const float* beta2 = (const float*)d_in[12];

    const int E = in_sizes[2];
    const int N = in_sizes[0] / IN_DIM;
    const int nseg = NREL * N;

    // workspace layout (floats then ints)
    float* PA = (float*)d_ws;
    float* PB = PA + (size_t)N * 64;
    float* PR = PB + (size_t)N * 64;
    float* H  = PR + (size_t)N * 64;
    int* cnt    = (int*)(H + (size_t)N * 64);
    int* excl   = cnt + nseg;
    int* rowptr = excl + nseg;          // nseg + 1
    int* cursor = rowptr + nseg + 1;
    int* colA   = cursor + nseg;        // E
    int* bsum   = colA + E;             // 256
    int* boff   = bsum + 256;           // 256

    const int* esrc = ei;
    const int* edst = ei + E;

    // ---- CSR build ----
    zero_ints<<<(nseg + 255) / 256, 256, 0, stream>>>(cnt, nseg);
    count_edges<<<(E + 255) / 256, 256, 0, stream>>>(et, edst, cnt, E, N);
    int nb = (nseg + SCAN_T * SCAN_I - 1) / (SCAN_T * SCAN_I);
    scan_phase1<<<nb, SCAN_T, 0, stream>>>(cnt, excl, bsum, nseg);
    scan_phase1<<<1, SCAN_T, 0, stream>>>(bsum, boff, nullptr, nb);
    scan_phase3<<<(nseg + 255) / 256, 256, 0, stream>>>(excl, boff, rowptr, cursor,
                                                        nseg, E);
    fill_edges<<<(E + 255) / 256, 256, 0, stream>>>(et, esrc, edst, cursor, colA, E, N);

    // ---- Layer 1 ----
    int gblocks = (N + 63) / 64;
    gemm_bcast<IN_DIM><<<gblocks, 256, 0, stream>>>(
        x, W1, W1 + (size_t)IN_DIM * 64, root1, PA, PB, PR, N);
    agg_ln_kernel<<<(N + 3) / 4, 256, 0, stream>>>(PA, PB, PR, rowptr, colA, b1, g1,
                                                   beta1, H, N, 1);

    // ---- Layer 2 ----
    gemm_bcast<HID><<<gblocks, 256, 0, stream>>>(
        H, W2, W2 + (size_t)HID * 64, root2, PA, PB, PR, N);
    agg_ln_kernel<<<(N + 3) / 4, 256, 0, stream>>>(PA, PB, PR, rowptr, colA, b2, g2,
                                                   beta2, (float*)d_out, N, 0);
}

// Round 3
// 368.666 us; speedup vs baseline: 1.6167x; 1.2334x over previous
//
#include <hip/hip_runtime.h>
#include <hip/hip_bf16.h>
#include <math.h>

#define IN_DIM 128
#define HID 64
#define NREL 2

// ---------------------------------------------------------------------------
// Utility: zero an int array
// ---------------------------------------------------------------------------
__global__ void zero_ints(int* p, int n) {
    int i = blockIdx.x * blockDim.x + threadIdx.x;
    if (i < n) p[i] = 0;
}

// ---------------------------------------------------------------------------
// CSR build: count edges per (rel, dst)
// ---------------------------------------------------------------------------
__global__ void count_edges(const int* __restrict__ et, const int* __restrict__ dst,
                            int* __restrict__ cnt, int E, int N) {
    int e = blockIdx.x * blockDim.x + threadIdx.x;
    if (e < E) {
        atomicAdd(&cnt[et[e] * N + dst[e]], 1);
    }
}

// ---------------------------------------------------------------------------
// Scan phase 1: per-block (1024 elems) exclusive scan + block sums
// ---------------------------------------------------------------------------
#define SCAN_T 256
#define SCAN_I 4
__global__ void scan_phase1(const int* __restrict__ in, int* __restrict__ excl,
                            int* __restrict__ bsum, int n) {
    __shared__ int sdata[SCAN_T];
    int b = blockIdx.x;
    int t = threadIdx.x;
    int base = b * SCAN_T * SCAN_I;
    int v[SCAN_I];
    int s = 0;
#pragma unroll
    for (int i = 0; i < SCAN_I; ++i) {
        int idx = base + t * SCAN_I + i;
        v[i] = (idx < n) ? in[idx] : 0;
        s += v[i];
    }
    sdata[t] = s;
    __syncthreads();
    for (int off = 1; off < SCAN_T; off <<= 1) {
        int x = (t >= off) ? sdata[t - off] : 0;
        __syncthreads();
        sdata[t] += x;
        __syncthreads();
    }
    int run = sdata[t] - s;
    if (bsum && t == SCAN_T - 1) bsum[b] = sdata[SCAN_T - 1];
#pragma unroll
    for (int i = 0; i < SCAN_I; ++i) {
        int idx = base + t * SCAN_I + i;
        if (idx < n) excl[idx] = run;
        run += v[i];
    }
}

// ---------------------------------------------------------------------------
// Scan phase 3: add block offsets, produce rowptr and cursor copies
// ---------------------------------------------------------------------------
__global__ void scan_phase3(const int* __restrict__ excl, const int* __restrict__ boff,
                            int* __restrict__ rowptr, int* __restrict__ cursor,
                            int n, int total) {
    int i = blockIdx.x * blockDim.x + threadIdx.x;
    if (i < n) {
        int v = excl[i] + boff[i / (SCAN_T * SCAN_I)];
        rowptr[i] = v;
        cursor[i] = v;
    }
    if (i == 0) rowptr[n] = total;
}

// ---------------------------------------------------------------------------
// CSR fill: scatter src indices into relation/dst-grouped slots
// ---------------------------------------------------------------------------
__global__ void fill_edges(const int* __restrict__ et, const int* __restrict__ src,
                           const int* __restrict__ dst, int* __restrict__ cursor,
                           int* __restrict__ col, int E, int N) {
    int e = blockIdx.x * blockDim.x + threadIdx.x;
    if (e < E) {
        int slot = atomicAdd(&cursor[et[e] * N + dst[e]], 1);
        col[slot] = src[e];
    }
}

// ---------------------------------------------------------------------------
// Tall-skinny packed GEMM, no LDS, no barriers. (unchanged from R2)
// ---------------------------------------------------------------------------
__device__ __forceinline__ float bcast_lane(float v, int srclane) {
    return __int_as_float(__builtin_amdgcn_readlane(__float_as_int(v), srclane));
}

template <int K>
__global__ __launch_bounds__(256, 3) void gemm_bcast(
    const float* __restrict__ X,
    const float* __restrict__ Wa, const float* __restrict__ Wb,
    const float* __restrict__ Wr,
    float* __restrict__ PA, float* __restrict__ PB, float* __restrict__ PR,
    int M) {
    const int lane = threadIdx.x & 63;
    const int row0 = blockIdx.x * 64 + (threadIdx.x >> 6) * 16;

    float xe[16], xo[16];
#pragma unroll
    for (int r = 0; r < 16; ++r) {
        int row = row0 + r;
        float2 v = make_float2(0.f, 0.f);
        if (row < M && 2 * lane < K)
            v = *reinterpret_cast<const float2*>(X + (size_t)row * K + 2 * lane);
        xe[r] = v.x;
        xo[r] = v.y;
    }

    float a0[16], a1[16], a2[16];
#pragma unroll
    for (int r = 0; r < 16; ++r) { a0[r] = 0.f; a1[r] = 0.f; a2[r] = 0.f; }

    float bufA[3][4], bufB[3][4];

#define LOADW(BUF, KB)                                                        \
    {                                                                         \
        _Pragma("unroll") for (int kk = 0; kk < 4; ++kk) {                    \
            BUF[0][kk] = Wa[(size_t)((KB) + kk) * 64 + lane];                 \
            BUF[1][kk] = Wb[(size_t)((KB) + kk) * 64 + lane];                 \
            BUF[2][kk] = Wr[(size_t)((KB) + kk) * 64 + lane];                 \
        }                                                                     \
    }

#define COMPUTE(BUF, KB)                                                      \
    {                                                                         \
        _Pragma("unroll") for (int kp = 0; kp < 2; ++kp) {                    \
            const int sl = ((KB) >> 1) + kp;                                  \
            _Pragma("unroll") for (int r = 0; r < 16; ++r) {                  \
                float ve = bcast_lane(xe[r], sl);                             \
                a0[r] = fmaf(ve, BUF[0][2 * kp], a0[r]);                      \
                a1[r] = fmaf(ve, BUF[1][2 * kp], a1[r]);                      \
                a2[r] = fmaf(ve, BUF[2][2 * kp], a2[r]);                      \
                float vo = bcast_lane(xo[r], sl);                             \
                a0[r] = fmaf(vo, BUF[0][2 * kp + 1], a0[r]);                  \
                a1[r] = fmaf(vo, BUF[1][2 * kp + 1], a1[r]);                  \
                a2[r] = fmaf(vo, BUF[2][2 * kp + 1], a2[r]);                  \
            }                                                                 \
        }                                                                     \
    }

    LOADW(bufA, 0);
    int k0 = 0;
    for (; k0 < K - 8; k0 += 8) {
        LOADW(bufB, k0 + 4);
        COMPUTE(bufA, k0);
        LOADW(bufA, k0 + 8);
        COMPUTE(bufB, k0 + 4);
    }
    LOADW(bufB, k0 + 4);
    COMPUTE(bufA, k0);
    COMPUTE(bufB, k0 + 4);

#undef LOADW
#undef COMPUTE

#pragma unroll
    for (int r = 0; r < 16; ++r) {
        int row = row0 + r;
        if (row < M) {
            PA[(size_t)row * 64 + lane] = a0[r];
            PB[(size_t)row * 64 + lane] = a1[r];
            PR[(size_t)row * 64 + lane] = a2[r];
        }
    }
}

// ---------------------------------------------------------------------------
// Aggregate + LayerNorm (+ optional exact GELU), v2: 4-edge-parallel gather.
//
// Wave = 1 node. Lanes = 4 sub-groups x 16. Sub-group `sub` handles edges
// {beg+sub, beg+sub+4, ...}; lane loads float4 of the source row (features
// 4c..4c+3, c = lane&15). One wave load instruction = 4 edge rows = 1 KB.
// Unroll-by-2 puts 8 edges in flight. Cross-sub __shfl_xor(16,32) merges
// partials; LN runs over 16 lanes x 4 features.
// ---------------------------------------------------------------------------
__device__ __forceinline__ float4 shfl_xor_f4(float4 v, int m) {
    return make_float4(__shfl_xor(v.x, m), __shfl_xor(v.y, m),
                       __shfl_xor(v.z, m), __shfl_xor(v.w, m));
}

__global__ __launch_bounds__(256) void agg_ln_kernel(
    const float* __restrict__ PA, const float* __restrict__ PB,
    const float* __restrict__ PR,
    const int* __restrict__ rowptr, const int* __restrict__ col,
    const float* __restrict__ bias, const float* __restrict__ g,
    const float* __restrict__ beta,
    float* __restrict__ out, int N, int gelu) {
    const int t = threadIdx.x;
    const int lane = t & 63;
    const int sub = lane >> 4;   // which edge within a quad
    const int c = lane & 15;     // feature quad index
    const int node = blockIdx.x * 4 + (t >> 6);
    if (node >= N) return;

    float4 acc = *reinterpret_cast<const float4*>(PR + (size_t)node * 64 + c * 4);
    {
        float4 b4 = *reinterpret_cast<const float4*>(bias + c * 4);
        acc.x += b4.x; acc.y += b4.y; acc.z += b4.z; acc.w += b4.w;
    }

#pragma unroll
    for (int r = 0; r < 2; ++r) {
        const float* __restrict__ P = r ? PB : PA;
        const int beg = rowptr[r * N + node];
        const int end = rowptr[r * N + node + 1];
        float4 s0 = make_float4(0.f, 0.f, 0.f, 0.f);
        float4 s1 = make_float4(0.f, 0.f, 0.f, 0.f);
        for (int i = beg + sub; i < end; i += 8) {
            const float4 v0 =
                *reinterpret_cast<const float4*>(P + (size_t)col[i] * 64 + c * 4);
            s0.x += v0.x; s0.y += v0.y; s0.z += v0.z; s0.w += v0.w;
            const int j = i + 4;
            if (j < end) {
                const float4 v1 =
                    *reinterpret_cast<const float4*>(P + (size_t)col[j] * 64 + c * 4);
                s1.x += v1.x; s1.y += v1.y; s1.z += v1.z; s1.w += v1.w;
            }
        }
        s0.x += s1.x; s0.y += s1.y; s0.z += s1.z; s0.w += s1.w;
        float4 o = shfl_xor_f4(s0, 16);
        s0.x += o.x; s0.y += o.y; s0.z += o.z; s0.w += o.w;
        o = shfl_xor_f4(s0, 32);
        s0.x += o.x; s0.y += o.y; s0.z += o.z; s0.w += o.w;
        const int deg = end - beg;
        if (deg > 0) {
            const float inv = 1.f / (float)deg;
            acc.x += s0.x * inv; acc.y += s0.y * inv;
            acc.z += s0.z * inv; acc.w += s0.w * inv;
        }
    }

    // LayerNorm over 64 features (16 lanes x float4; groups replicated x4)
    float ps = acc.x + acc.y + acc.z + acc.w;
#pragma unroll
    for (int off = 1; off <= 8; off <<= 1) ps += __shfl_xor(ps, off);
    const float mu = ps * (1.f / 64.f);
    const float4 d = make_float4(acc.x - mu, acc.y - mu, acc.z - mu, acc.w - mu);
    float vs = d.x * d.x + d.y * d.y + d.z * d.z + d.w * d.w;
#pragma unroll
    for (int off = 1; off <= 8; off <<= 1) vs += __shfl_xor(vs, off);
    const float rstd = 1.f / sqrtf(vs * (1.f / 64.f) + 1e-5f);

    const float4 g4 = *reinterpret_cast<const float4*>(g + c * 4);
    const float4 be4 = *reinterpret_cast<const float4*>(beta + c * 4);
    float4 y;
    y.x = d.x * rstd * g4.x + be4.x;
    y.y = d.y * rstd * g4.y + be4.y;
    y.z = d.z * rstd * g4.z + be4.z;
    y.w = d.w * rstd * g4.w + be4.w;

    if (gelu) {
        y.x = 0.5f * y.x * (1.f + erff(y.x * 0.70710678118654752440f));
        y.y = 0.5f * y.y * (1.f + erff(y.y * 0.70710678118654752440f));
        y.z = 0.5f * y.z * (1.f + erff(y.z * 0.70710678118654752440f));
        y.w = 0.5f * y.w * (1.f + erff(y.w * 0.70710678118654752440f));
    }

    if (sub == 0)
        *reinterpret_cast<float4*>(out + (size_t)node * 64 + c * 4) = y;
}

// ---------------------------------------------------------------------------
// Launch
// ---------------------------------------------------------------------------
extern "C" void kernel_launch(void* const* d_in, const int* in_sizes, int n_in,
                              void* d_out, int out_size, void* d_ws, size_t ws_size,
                              hipStream_t stream) {
    const float* x = (const float*)d_in[0];
    const int* ei = (const int*)d_in[1];   // [2][E]: src row then dst row
    const int* et = (const int*)d_in[2];   // [E]
    const float* W1 = (const float*)d_in[3];    // [2][128][64]
    const float* root1 = (const float*)d_in[4]; // [128][64]
    const float* b1 = (const float*)d_in[5];
    const float* g1 = (const float*)d_in[6];
    const float* beta1 = (const float*)d_in[7];
    const float* W2 = (const float*)d_in[8];    // [2][64][64]
    const float* root2 = (const float*)d_in[9]; // [64][64]
    const float* b2 = (const float*)d_in[10];
    const float* g2 = (const float*)d_in[11];
    const float* beta2 = (const float*)d_in[12];

    const int E = in_sizes[2];
    const int N = in_sizes[0] / IN_DIM;
    const int nseg = NREL * N;

    // workspace layout (floats then ints)
    float* PA = (float*)d_ws;
    float* PB = PA + (size_t)N * 64;
    float* PR = PB + (size_t)N * 64;
    float* H  = PR + (size_t)N * 64;
    int* cnt    = (int*)(H + (size_t)N * 64);
    int* excl   = cnt + nseg;
    int* rowptr = excl + nseg;          // nseg + 1
    int* cursor = rowptr + nseg + 1;
    int* colA   = cursor + nseg;        // E
    int* bsum   = colA + E;             // 256
    int* boff   = bsum + 256;           // 256

    const int* esrc = ei;
    const int* edst = ei + E;

    // ---- CSR build ----
    zero_ints<<<(nseg + 255) / 256, 256, 0, stream>>>(cnt, nseg);
    count_edges<<<(E + 255) / 256, 256, 0, stream>>>(et, edst, cnt, E, N);
    int nb = (nseg + SCAN_T * SCAN_I - 1) / (SCAN_T * SCAN_I);
    scan_phase1<<<nb, SCAN_T, 0, stream>>>(cnt, excl, bsum, nseg);
    scan_phase1<<<1, SCAN_T, 0, stream>>>(bsum, boff, nullptr, nb);
    scan_phase3<<<(nseg + 255) / 256, 256, 0, stream>>>(excl, boff, rowptr, cursor,
                                                        nseg, E);
    fill_edges<<<(E + 255) / 256, 256, 0, stream>>>(et, esrc, edst, cursor, colA, E, N);

    // ---- Layer 1 ----
    int gblocks = (N + 63) / 64;
    gemm_bcast<IN_DIM><<<gblocks, 256, 0, stream>>>(
        x, W1, W1 + (size_t)IN_DIM * 64, root1, PA, PB, PR, N);
    agg_ln_kernel<<<(N + 3) / 4, 256, 0, stream>>>(PA, PB, PR, rowptr, colA, b1, g1,
                                                   beta1, H, N, 1);

    // ---- Layer 2 ----
    gemm_bcast<HID><<<gblocks, 256, 0, stream>>>(
        H, W2, W2 + (size_t)HID * 64, root2, PA, PB, PR, N);
    agg_ln_kernel<<<(N + 3) / 4, 256, 0, stream>>>(PA, PB, PR, rowptr, colA, b2, g2,
                                                   beta2, (float*)d_out, N, 0);
}

// Round 4
// 334.102 us; speedup vs baseline: 1.7840x; 1.1035x over previous
//
#include <hip/hip_runtime.h>
#include <hip/hip_bf16.h>
#include <math.h>

#define IN_DIM 128
#define HID 64
#define NREL 2

// ---------------------------------------------------------------------------
// Utility: zero an int array
// ---------------------------------------------------------------------------
__global__ void zero_ints(int* p, int n) {
    int i = blockIdx.x * blockDim.x + threadIdx.x;
    if (i < n) p[i] = 0;
}

// ---------------------------------------------------------------------------
// CSR build: count edges per (rel, dst)
// ---------------------------------------------------------------------------
__global__ void count_edges(const int* __restrict__ et, const int* __restrict__ dst,
                            int* __restrict__ cnt, int E, int N) {
    int e = blockIdx.x * blockDim.x + threadIdx.x;
    if (e < E) {
        atomicAdd(&cnt[et[e] * N + dst[e]], 1);
    }
}

// ---------------------------------------------------------------------------
// Scan phase 1: per-block (1024 elems) exclusive scan + block sums
// ---------------------------------------------------------------------------
#define SCAN_T 256
#define SCAN_I 4
__global__ void scan_phase1(const int* __restrict__ in, int* __restrict__ excl,
                            int* __restrict__ bsum, int n) {
    __shared__ int sdata[SCAN_T];
    int b = blockIdx.x;
    int t = threadIdx.x;
    int base = b * SCAN_T * SCAN_I;
    int v[SCAN_I];
    int s = 0;
#pragma unroll
    for (int i = 0; i < SCAN_I; ++i) {
        int idx = base + t * SCAN_I + i;
        v[i] = (idx < n) ? in[idx] : 0;
        s += v[i];
    }
    sdata[t] = s;
    __syncthreads();
    for (int off = 1; off < SCAN_T; off <<= 1) {
        int x = (t >= off) ? sdata[t - off] : 0;
        __syncthreads();
        sdata[t] += x;
        __syncthreads();
    }
    int run = sdata[t] - s;
    if (bsum && t == SCAN_T - 1) bsum[b] = sdata[SCAN_T - 1];
#pragma unroll
    for (int i = 0; i < SCAN_I; ++i) {
        int idx = base + t * SCAN_I + i;
        if (idx < n) excl[idx] = run;
        run += v[i];
    }
}

// ---------------------------------------------------------------------------
// Scan phase 3: add block offsets, produce rowptr and cursor copies
// ---------------------------------------------------------------------------
__global__ void scan_phase3(const int* __restrict__ excl, const int* __restrict__ boff,
                            int* __restrict__ rowptr, int* __restrict__ cursor,
                            int n, int total) {
    int i = blockIdx.x * blockDim.x + threadIdx.x;
    if (i < n) {
        int v = excl[i] + boff[i / (SCAN_T * SCAN_I)];
        rowptr[i] = v;
        cursor[i] = v;
    }
    if (i == 0) rowptr[n] = total;
}

// ---------------------------------------------------------------------------
// CSR fill: scatter src indices into relation/dst-grouped slots
// ---------------------------------------------------------------------------
__global__ void fill_edges(const int* __restrict__ et, const int* __restrict__ src,
                           const int* __restrict__ dst, int* __restrict__ cursor,
                           int* __restrict__ col, int E, int N) {
    int e = blockIdx.x * blockDim.x + threadIdx.x;
    if (e < E) {
        int slot = atomicAdd(&cursor[et[e] * N + dst[e]], 1);
        col[slot] = src[e];
    }
}

// ---------------------------------------------------------------------------
// W repack: [K][64]x3 sources -> Wp[K/4][192] float4 (4 consecutive k per
// lane-column). Lets the gemm load 4 k-steps of its 3 columns with 3
// global_load_dwordx4.
// ---------------------------------------------------------------------------
__global__ void repack_w(const float* __restrict__ Wa, const float* __restrict__ Wb,
                         const float* __restrict__ Wr, float4* __restrict__ Wp,
                         int K) {
    int tid = blockIdx.x * blockDim.x + threadIdx.x;
    int total = (K / 4) * 192;
    if (tid >= total) return;
    int kc = tid / 192, c = tid % 192;
    const float* Wg = (c < 64) ? Wa : (c < 128) ? Wb : Wr;
    int cc = c & 63;
    float4 v;
    v.x = Wg[(size_t)(kc * 4 + 0) * 64 + cc];
    v.y = Wg[(size_t)(kc * 4 + 1) * 64 + cc];
    v.z = Wg[(size_t)(kc * 4 + 2) * 64 + cc];
    v.w = Wg[(size_t)(kc * 4 + 3) * 64 + cc];
    Wp[tid] = v;
}

// ---------------------------------------------------------------------------
// Tall-skinny packed GEMM v3: X broadcast via the SCALAR pipe.
// [M,K] @ ([K,64]|[K,64]|[K,64]) -> PA, PB, PR   (fp32 VALU)
//
// Wave = 8 rows x 192 cols; lane owns cols {l, l+64, l+128}. Row indices are
// wave-uniform (wave id via readfirstlane), so x[row][k0..k0+3] loads are
// s_load_dwordx4 on the scalar pipe (zero VALU cost). W comes from the
// repacked [K/4][192]xfloat4 buffer: 3 dwordx4 vector loads per 4-k chunk.
// Per 4-k chunk: 96 FMA + 3 vloads => ~93% FMA density, no barriers, no LDS,
// no readlanes. Double-buffered chunks with static register indices.
// ---------------------------------------------------------------------------
template <int K>
__global__ __launch_bounds__(256) void gemm_srow(
    const float* __restrict__ X,
    const float4* __restrict__ Wp,
    float* __restrict__ PA, float* __restrict__ PB, float* __restrict__ PR,
    int M) {
    const int lane = threadIdx.x & 63;
    const int wv = __builtin_amdgcn_readfirstlane((int)(threadIdx.x >> 6));
    const int row0 = blockIdx.x * 32 + wv * 8;

    // Wave-uniform clamped row bases (elements).
    int roff[8];
#pragma unroll
    for (int r = 0; r < 8; ++r) {
        int rr = row0 + r;
        if (rr > M - 1) rr = M - 1;
        roff[r] = rr * K;
    }

    float acc[8][3];
#pragma unroll
    for (int r = 0; r < 8; ++r) { acc[r][0] = 0.f; acc[r][1] = 0.f; acc[r][2] = 0.f; }

    float4 xA[8], xB[8];   // wave-uniform -> SGPRs
    float4 wA[3], wB[3];   // per-lane W chunk

#define LOADX(BUF, KB)                                                        \
    {                                                                         \
        _Pragma("unroll") for (int r = 0; r < 8; ++r)                         \
            BUF[r] = *reinterpret_cast<const float4*>(X + roff[r] + (KB));    \
    }
#define LOADW(BUF, KB)                                                        \
    {                                                                         \
        _Pragma("unroll") for (int gidx = 0; gidx < 3; ++gidx)                \
            BUF[gidx] = Wp[(size_t)((KB) >> 2) * 192 + gidx * 64 + lane];     \
    }
#define CJ(BX, BW, C)                                                         \
    {                                                                         \
        _Pragma("unroll") for (int r = 0; r < 8; ++r) {                       \
            acc[r][0] = fmaf(BX[r].C, BW[0].C, acc[r][0]);                    \
            acc[r][1] = fmaf(BX[r].C, BW[1].C, acc[r][1]);                    \
            acc[r][2] = fmaf(BX[r].C, BW[2].C, acc[r][2]);                    \
        }                                                                     \
    }
#define COMPUTE(BX, BW) CJ(BX, BW, x) CJ(BX, BW, y) CJ(BX, BW, z) CJ(BX, BW, w)

    LOADX(xA, 0);
    LOADW(wA, 0);
    int k0 = 0;
    for (; k0 < K - 8; k0 += 8) {
        LOADX(xB, k0 + 4);
        LOADW(wB, k0 + 4);
        COMPUTE(xA, wA);
        LOADX(xA, k0 + 8);
        LOADW(wA, k0 + 8);
        COMPUTE(xB, wB);
    }
    LOADX(xB, k0 + 4);
    LOADW(wB, k0 + 4);
    COMPUTE(xA, wA);
    COMPUTE(xB, wB);

#undef LOADX
#undef LOADW
#undef CJ
#undef COMPUTE

#pragma unroll
    for (int r = 0; r < 8; ++r) {
        int row = row0 + r;
        if (row < M) {
            PA[(size_t)row * 64 + lane] = acc[r][0];
            PB[(size_t)row * 64 + lane] = acc[r][1];
            PR[(size_t)row * 64 + lane] = acc[r][2];
        }
    }
}

// ---------------------------------------------------------------------------
// Aggregate + LayerNorm (+ optional exact GELU), 4-edge-parallel gather.
// (unchanged from R3)
// ---------------------------------------------------------------------------
__device__ __forceinline__ float4 shfl_xor_f4(float4 v, int m) {
    return make_float4(__shfl_xor(v.x, m), __shfl_xor(v.y, m),
                       __shfl_xor(v.z, m), __shfl_xor(v.w, m));
}

__global__ __launch_bounds__(256) void agg_ln_kernel(
    const float* __restrict__ PA, const float* __restrict__ PB,
    const float* __restrict__ PR,
    const int* __restrict__ rowptr, const int* __restrict__ col,
    const float* __restrict__ bias, const float* __restrict__ g,
    const float* __restrict__ beta,
    float* __restrict__ out, int N, int gelu) {
    const int t = threadIdx.x;
    const int lane = t & 63;
    const int sub = lane >> 4;   // which edge within a quad
    const int c = lane & 15;     // feature quad index
    const int node = blockIdx.x * 4 + (t >> 6);
    if (node >= N) return;

    float4 acc = *reinterpret_cast<const float4*>(PR + (size_t)node * 64 + c * 4);
    {
        float4 b4 = *reinterpret_cast<const float4*>(bias + c * 4);
        acc.x += b4.x; acc.y += b4.y; acc.z += b4.z; acc.w += b4.w;
    }

#pragma unroll
    for (int r = 0; r < 2; ++r) {
        const float* __restrict__ P = r ? PB : PA;
        const int beg = rowptr[r * N + node];
        const int end = rowptr[r * N + node + 1];
        float4 s0 = make_float4(0.f, 0.f, 0.f, 0.f);
        float4 s1 = make_float4(0.f, 0.f, 0.f, 0.f);
        for (int i = beg + sub; i < end; i += 8) {
            const float4 v0 =
                *reinterpret_cast<const float4*>(P + (size_t)col[i] * 64 + c * 4);
            s0.x += v0.x; s0.y += v0.y; s0.z += v0.z; s0.w += v0.w;
            const int j = i + 4;
            if (j < end) {
                const float4 v1 =
                    *reinterpret_cast<const float4*>(P + (size_t)col[j] * 64 + c * 4);
                s1.x += v1.x; s1.y += v1.y; s1.z += v1.z; s1.w += v1.w;
            }
        }
        s0.x += s1.x; s0.y += s1.y; s0.z += s1.z; s0.w += s1.w;
        float4 o = shfl_xor_f4(s0, 16);
        s0.x += o.x; s0.y += o.y; s0.z += o.z; s0.w += o.w;
        o = shfl_xor_f4(s0, 32);
        s0.x += o.x; s0.y += o.y; s0.z += o.z; s0.w += o.w;
        const int deg = end - beg;
        if (deg > 0) {
            const float inv = 1.f / (float)deg;
            acc.x += s0.x * inv; acc.y += s0.y * inv;
            acc.z += s0.z * inv; acc.w += s0.w * inv;
        }
    }

    // LayerNorm over 64 features (16 lanes x float4; groups replicated x4)
    float ps = acc.x + acc.y + acc.z + acc.w;
#pragma unroll
    for (int off = 1; off <= 8; off <<= 1) ps += __shfl_xor(ps, off);
    const float mu = ps * (1.f / 64.f);
    const float4 d = make_float4(acc.x - mu, acc.y - mu, acc.z - mu, acc.w - mu);
    float vs = d.x * d.x + d.y * d.y + d.z * d.z + d.w * d.w;
#pragma unroll
    for (int off = 1; off <= 8; off <<= 1) vs += __shfl_xor(vs, off);
    const float rstd = 1.f / sqrtf(vs * (1.f / 64.f) + 1e-5f);

    const float4 g4 = *reinterpret_cast<const float4*>(g + c * 4);
    const float4 be4 = *reinterpret_cast<const float4*>(beta + c * 4);
    float4 y;
    y.x = d.x * rstd * g4.x + be4.x;
    y.y = d.y * rstd * g4.y + be4.y;
    y.z = d.z * rstd * g4.z + be4.z;
    y.w = d.w * rstd * g4.w + be4.w;

    if (gelu) {
        y.x = 0.5f * y.x * (1.f + erff(y.x * 0.70710678118654752440f));
        y.y = 0.5f * y.y * (1.f + erff(y.y * 0.70710678118654752440f));
        y.z = 0.5f * y.z * (1.f + erff(y.z * 0.70710678118654752440f));
        y.w = 0.5f * y.w * (1.f + erff(y.w * 0.70710678118654752440f));
    }

    if (sub == 0)
        *reinterpret_cast<float4*>(out + (size_t)node * 64 + c * 4) = y;
}

// ---------------------------------------------------------------------------
// Launch
// ---------------------------------------------------------------------------
extern "C" void kernel_launch(void* const* d_in, const int* in_sizes, int n_in,
                              void* d_out, int out_size, void* d_ws, size_t ws_size,
                              hipStream_t stream) {
    const float* x = (const float*)d_in[0];
    const int* ei = (const int*)d_in[1];   // [2][E]: src row then dst row
    const int* et = (const int*)d_in[2];   // [E]
    const float* W1 = (const float*)d_in[3];    // [2][128][64]
    const float* root1 = (const float*)d_in[4]; // [128][64]
    const float* b1 = (const float*)d_in[5];
    const float* g1 = (const float*)d_in[6];
    const float* beta1 = (const float*)d_in[7];
    const float* W2 = (const float*)d_in[8];    // [2][64][64]
    const float* root2 = (const float*)d_in[9]; // [64][64]
    const float* b2 = (const float*)d_in[10];
    const float* g2 = (const float*)d_in[11];
    const float* beta2 = (const float*)d_in[12];

    const int E = in_sizes[2];
    const int N = in_sizes[0] / IN_DIM;
    const int nseg = NREL * N;

    // workspace layout: float4-aligned W packs first, then floats, then ints
    float4* Wp1 = (float4*)d_ws;                       // (128/4)*192 = 6144
    float4* Wp2 = Wp1 + (IN_DIM / 4) * 192;            // (64/4)*192 = 3072
    float* PA = (float*)(Wp2 + (HID / 4) * 192);
    float* PB = PA + (size_t)N * 64;
    float* PR = PB + (size_t)N * 64;
    float* H  = PR + (size_t)N * 64;
    int* cnt    = (int*)(H + (size_t)N * 64);
    int* excl   = cnt + nseg;
    int* rowptr = excl + nseg;          // nseg + 1
    int* cursor = rowptr + nseg + 1;
    int* colA   = cursor + nseg;        // E
    int* bsum   = colA + E;             // 256
    int* boff   = bsum + 256;           // 256

    const int* esrc = ei;
    const int* edst = ei + E;

    // ---- CSR build ----
    zero_ints<<<(nseg + 255) / 256, 256, 0, stream>>>(cnt, nseg);
    count_edges<<<(E + 255) / 256, 256, 0, stream>>>(et, edst, cnt, E, N);
    int nb = (nseg + SCAN_T * SCAN_I - 1) / (SCAN_T * SCAN_I);
    scan_phase1<<<nb, SCAN_T, 0, stream>>>(cnt, excl, bsum, nseg);
    scan_phase1<<<1, SCAN_T, 0, stream>>>(bsum, boff, nullptr, nb);
    scan_phase3<<<(nseg + 255) / 256, 256, 0, stream>>>(excl, boff, rowptr, cursor,
                                                        nseg, E);
    fill_edges<<<(E + 255) / 256, 256, 0, stream>>>(et, esrc, edst, cursor, colA, E, N);

    // ---- W repack (both layers) ----
    repack_w<<<((IN_DIM / 4) * 192 + 255) / 256, 256, 0, stream>>>(
        W1, W1 + (size_t)IN_DIM * 64, root1, Wp1, IN_DIM);
    repack_w<<<((HID / 4) * 192 + 255) / 256, 256, 0, stream>>>(
        W2, W2 + (size_t)HID * 64, root2, Wp2, HID);

    // ---- Layer 1 ----
    int gblocks = (N + 31) / 32;
    gemm_srow<IN_DIM><<<gblocks, 256, 0, stream>>>(x, Wp1, PA, PB, PR, N);
    agg_ln_kernel<<<(N + 3) / 4, 256, 0, stream>>>(PA, PB, PR, rowptr, colA, b1, g1,
                                                   beta1, H, N, 1);

    // ---- Layer 2 ----
    gemm_srow<HID><<<gblocks, 256, 0, stream>>>(H, Wp2, PA, PB, PR, N);
    agg_ln_kernel<<<(N + 3) / 4, 256, 0, stream>>>(PA, PB, PR, rowptr, colA, b2, g2,
                                                   beta2, (float*)d_out, N, 0);
}

// Round 5
// 327.216 us; speedup vs baseline: 1.8215x; 1.0210x over previous
//
#include <hip/hip_runtime.h>
#include <hip/hip_bf16.h>
#include <math.h>

#define IN_DIM 128
#define HID 64
#define NREL 2

using f32x4 = __attribute__((ext_vector_type(4))) float;
using s16x8 = __attribute__((ext_vector_type(8))) short;

// fp32 -> bf16 (RNE) and back, via bit ops
__device__ __forceinline__ short f2bf(float f) {
    unsigned u = __float_as_uint(f);
    unsigned r = (u + 0x7fffu + ((u >> 16) & 1u)) >> 16;
    return (short)r;
}
__device__ __forceinline__ float bf2f(short b) {
    return __uint_as_float(((unsigned)(unsigned short)b) << 16);
}

// ---------------------------------------------------------------------------
// Utility: zero an int array
// ---------------------------------------------------------------------------
__global__ void zero_ints(int* p, int n) {
    int i = blockIdx.x * blockDim.x + threadIdx.x;
    if (i < n) p[i] = 0;
}

// ---------------------------------------------------------------------------
// CSR build: count edges per (rel, dst)
// ---------------------------------------------------------------------------
__global__ void count_edges(const int* __restrict__ et, const int* __restrict__ dst,
                            int* __restrict__ cnt, int E, int N) {
    int e = blockIdx.x * blockDim.x + threadIdx.x;
    if (e < E) {
        atomicAdd(&cnt[et[e] * N + dst[e]], 1);
    }
}

// ---------------------------------------------------------------------------
// Scan phase 1: per-block (1024 elems) exclusive scan + block sums
// ---------------------------------------------------------------------------
#define SCAN_T 256
#define SCAN_I 4
__global__ void scan_phase1(const int* __restrict__ in, int* __restrict__ excl,
                            int* __restrict__ bsum, int n) {
    __shared__ int sdata[SCAN_T];
    int b = blockIdx.x;
    int t = threadIdx.x;
    int base = b * SCAN_T * SCAN_I;
    int v[SCAN_I];
    int s = 0;
#pragma unroll
    for (int i = 0; i < SCAN_I; ++i) {
        int idx = base + t * SCAN_I + i;
        v[i] = (idx < n) ? in[idx] : 0;
        s += v[i];
    }
    sdata[t] = s;
    __syncthreads();
    for (int off = 1; off < SCAN_T; off <<= 1) {
        int x = (t >= off) ? sdata[t - off] : 0;
        __syncthreads();
        sdata[t] += x;
        __syncthreads();
    }
    int run = sdata[t] - s;
    if (bsum && t == SCAN_T - 1) bsum[b] = sdata[SCAN_T - 1];
#pragma unroll
    for (int i = 0; i < SCAN_I; ++i) {
        int idx = base + t * SCAN_I + i;
        if (idx < n) excl[idx] = run;
        run += v[i];
    }
}

// ---------------------------------------------------------------------------
// Scan phase 3: add block offsets, produce rowptr and cursor copies
// ---------------------------------------------------------------------------
__global__ void scan_phase3(const int* __restrict__ excl, const int* __restrict__ boff,
                            int* __restrict__ rowptr, int* __restrict__ cursor,
                            int n, int total) {
    int i = blockIdx.x * blockDim.x + threadIdx.x;
    if (i < n) {
        int v = excl[i] + boff[i / (SCAN_T * SCAN_I)];
        rowptr[i] = v;
        cursor[i] = v;
    }
    if (i == 0) rowptr[n] = total;
}

// ---------------------------------------------------------------------------
// CSR fill: scatter src indices into relation/dst-grouped slots
// ---------------------------------------------------------------------------
__global__ void fill_edges(const int* __restrict__ et, const int* __restrict__ src,
                           const int* __restrict__ dst, int* __restrict__ cursor,
                           int* __restrict__ col, int E, int N) {
    int e = blockIdx.x * blockDim.x + threadIdx.x;
    if (e < E) {
        int slot = atomicAdd(&cursor[et[e] * N + dst[e]], 1);
        col[slot] = src[e];
    }
}

// ---------------------------------------------------------------------------
// W repack into MFMA B-fragment order, split hi/lo bf16.
// Fragment layout (16x16x32 bf16 B operand): lane l holds col = c*16+(l&15),
// k = t*32 + (l>>4)*8 + j, j=0..7. Group index g = (c*T + t)*2 + part.
// Storage: Wf[g*512 + lane*8 + j] shorts -> one dwordx4 per (lane, g).
// Layer 1: T=4 (K=128), 96 groups; layer 2: T=2 (K=64), 48 groups.
// ---------------------------------------------------------------------------
__device__ __forceinline__ void repack_one(const float* Wa, const float* Wb,
                                           const float* Wr, short* Wf, int T,
                                           int idx) {
    int g = idx >> 9;
    int r = idx & 511;
    int lane = r >> 3;
    int j = r & 7;
    int part = g & 1;
    int ct = g >> 1;
    int t = ct % T;
    int c = ct / T;
    int col = c * 16 + (lane & 15);
    int k = t * 32 + ((lane >> 4) << 3) + j;
    const float* Wg = (col < 64) ? Wa : (col < 128) ? Wb : Wr;
    float v = Wg[(size_t)k * 64 + (col & 63)];
    short hi = f2bf(v);
    Wf[idx] = part ? f2bf(v - bf2f(hi)) : hi;
}

__global__ void repack_w_frag(const float* __restrict__ W1,
                              const float* __restrict__ root1,
                              const float* __restrict__ W2,
                              const float* __restrict__ root2,
                              short* __restrict__ Wf1, short* __restrict__ Wf2) {
    const int L1 = 12 * 4 * 2 * 512;  // 49152
    const int L2 = 12 * 2 * 2 * 512;  // 24576
    int tid = blockIdx.x * blockDim.x + threadIdx.x;
    if (tid < L1) {
        repack_one(W1, W1 + (size_t)IN_DIM * 64, root1, Wf1, 4, tid);
    } else if (tid < L1 + L2) {
        repack_one(W2, W2 + (size_t)HID * 64, root2, Wf2, 2, tid - L1);
    }
}

// ---------------------------------------------------------------------------
// Split-bf16 MFMA GEMM: [M,K] @ ([K,64]|[K,64]|[K,64]) -> PA, PB, PR.
// x = xh + xl (bf16 split); result = xh*Wh + xl*Wh + xh*Wl (fp32 acc),
// residual ~2^-17 relative => fp32-grade accuracy on the matrix pipe.
// Wave = 16 rows x 192 cols = 12 col-tiles; K stepped by 32 (T steps).
// A-frag: lane holds row=l&15, k=t*32+(l>>4)*8+{0..7} (fp32 load + split).
// B-frag: from repacked Wf (one dwordx4 per (c,t,part)).
// D-frag (m89-verified): col=lane&15, row=(lane>>4)*4+reg.
// No LDS, no barriers.
// ---------------------------------------------------------------------------
template <int K>
__global__ __launch_bounds__(256) void gemm_mfma(
    const float* __restrict__ X, const short* __restrict__ Wf,
    float* __restrict__ PA, float* __restrict__ PB, float* __restrict__ PR,
    int M) {
    constexpr int T = K / 32;
    const int lane = threadIdx.x & 63;
    const int row0 = (blockIdx.x * 4 + (threadIdx.x >> 6)) * 16;

    int arow = row0 + (lane & 15);
    if (arow > M - 1) arow = M - 1;
    const float* xr = X + (size_t)arow * K + ((lane >> 4) << 3);
    const s16x8* WfV = (const s16x8*)Wf;

    f32x4 acc[12];
#pragma unroll
    for (int c = 0; c < 12; ++c) acc[c] = (f32x4){0.f, 0.f, 0.f, 0.f};

#pragma unroll
    for (int t = 0; t < T; ++t) {
        const float4 a0 = *reinterpret_cast<const float4*>(xr + t * 32);
        const float4 a1 = *reinterpret_cast<const float4*>(xr + t * 32 + 4);
        const float av[8] = {a0.x, a0.y, a0.z, a0.w, a1.x, a1.y, a1.z, a1.w};
        s16x8 ah, al;
#pragma unroll
        for (int j = 0; j < 8; ++j) {
            short h = f2bf(av[j]);
            ah[j] = h;
            al[j] = f2bf(av[j] - bf2f(h));
        }
#pragma unroll
        for (int c = 0; c < 12; ++c) {
            s16x8 bh = WfV[(size_t)((c * T + t) * 2 + 0) * 64 + lane];
            s16x8 bl = WfV[(size_t)((c * T + t) * 2 + 1) * 64 + lane];
            acc[c] = __builtin_amdgcn_mfma_f32_16x16x32_bf16(ah, bh, acc[c], 0, 0, 0);
            acc[c] = __builtin_amdgcn_mfma_f32_16x16x32_bf16(al, bh, acc[c], 0, 0, 0);
            acc[c] = __builtin_amdgcn_mfma_f32_16x16x32_bf16(ah, bl, acc[c], 0, 0, 0);
        }
    }

    const int drow = row0 + ((lane >> 4) << 2);
    const int dcol = lane & 15;
#pragma unroll
    for (int c = 0; c < 12; ++c) {
        float* base = (c < 4) ? PA : (c < 8) ? PB : PR;
        const int cc = (c & 3) * 16 + dcol;
#pragma unroll
        for (int q = 0; q < 4; ++q) {
            const int row = drow + q;
            if (row < M) base[(size_t)row * 64 + cc] = acc[c][q];
        }
    }
}

// ---------------------------------------------------------------------------
// Aggregate + LayerNorm (+ optional exact GELU), 4-edge-parallel gather.
// (unchanged from R3/R4)
// ---------------------------------------------------------------------------
__device__ __forceinline__ float4 shfl_xor_f4(float4 v, int m) {
    return make_float4(__shfl_xor(v.x, m), __shfl_xor(v.y, m),
                       __shfl_xor(v.z, m), __shfl_xor(v.w, m));
}

__global__ __launch_bounds__(256) void agg_ln_kernel(
    const float* __restrict__ PA, const float* __restrict__ PB,
    const float* __restrict__ PR,
    const int* __restrict__ rowptr, const int* __restrict__ col,
    const float* __restrict__ bias, const float* __restrict__ g,
    const float* __restrict__ beta,
    float* __restrict__ out, int N, int gelu) {
    const int t = threadIdx.x;
    const int lane = t & 63;
    const int sub = lane >> 4;   // which edge within a quad
    const int c = lane & 15;     // feature quad index
    const int node = blockIdx.x * 4 + (t >> 6);
    if (node >= N) return;

    float4 acc = *reinterpret_cast<const float4*>(PR + (size_t)node * 64 + c * 4);
    {
        float4 b4 = *reinterpret_cast<const float4*>(bias + c * 4);
        acc.x += b4.x; acc.y += b4.y; acc.z += b4.z; acc.w += b4.w;
    }

#pragma unroll
    for (int r = 0; r < 2; ++r) {
        const float* __restrict__ P = r ? PB : PA;
        const int beg = rowptr[r * N + node];
        const int end = rowptr[r * N + node + 1];
        float4 s0 = make_float4(0.f, 0.f, 0.f, 0.f);
        float4 s1 = make_float4(0.f, 0.f, 0.f, 0.f);
        for (int i = beg + sub; i < end; i += 8) {
            const float4 v0 =
                *reinterpret_cast<const float4*>(P + (size_t)col[i] * 64 + c * 4);
            s0.x += v0.x; s0.y += v0.y; s0.z += v0.z; s0.w += v0.w;
            const int j = i + 4;
            if (j < end) {
                const float4 v1 =
                    *reinterpret_cast<const float4*>(P + (size_t)col[j] * 64 + c * 4);
                s1.x += v1.x; s1.y += v1.y; s1.z += v1.z; s1.w += v1.w;
            }
        }
        s0.x += s1.x; s0.y += s1.y; s0.z += s1.z; s0.w += s1.w;
        float4 o = shfl_xor_f4(s0, 16);
        s0.x += o.x; s0.y += o.y; s0.z += o.z; s0.w += o.w;
        o = shfl_xor_f4(s0, 32);
        s0.x += o.x; s0.y += o.y; s0.z += o.z; s0.w += o.w;
        const int deg = end - beg;
        if (deg > 0) {
            const float inv = 1.f / (float)deg;
            acc.x += s0.x * inv; acc.y += s0.y * inv;
            acc.z += s0.z * inv; acc.w += s0.w * inv;
        }
    }

    // LayerNorm over 64 features (16 lanes x float4; groups replicated x4)
    float ps = acc.x + acc.y + acc.z + acc.w;
#pragma unroll
    for (int off = 1; off <= 8; off <<= 1) ps += __shfl_xor(ps, off);
    const float mu = ps * (1.f / 64.f);
    const float4 d = make_float4(acc.x - mu, acc.y - mu, acc.z - mu, acc.w - mu);
    float vs = d.x * d.x + d.y * d.y + d.z * d.z + d.w * d.w;
#pragma unroll
    for (int off = 1; off <= 8; off <<= 1) vs += __shfl_xor(vs, off);
    const float rstd = 1.f / sqrtf(vs * (1.f / 64.f) + 1e-5f);

    const float4 g4 = *reinterpret_cast<const float4*>(g + c * 4);
    const float4 be4 = *reinterpret_cast<const float4*>(beta + c * 4);
    float4 y;
    y.x = d.x * rstd * g4.x + be4.x;
    y.y = d.y * rstd * g4.y + be4.y;
    y.z = d.z * rstd * g4.z + be4.z;
    y.w = d.w * rstd * g4.w + be4.w;

    if (gelu) {
        y.x = 0.5f * y.x * (1.f + erff(y.x * 0.70710678118654752440f));
        y.y = 0.5f * y.y * (1.f + erff(y.y * 0.70710678118654752440f));
        y.z = 0.5f * y.z * (1.f + erff(y.z * 0.70710678118654752440f));
        y.w = 0.5f * y.w * (1.f + erff(y.w * 0.70710678118654752440f));
    }

    if (sub == 0)
        *reinterpret_cast<float4*>(out + (size_t)node * 64 + c * 4) = y;
}

// ---------------------------------------------------------------------------
// Launch
// ---------------------------------------------------------------------------
extern "C" void kernel_launch(void* const* d_in, const int* in_sizes, int n_in,
                              void* d_out, int out_size, void* d_ws, size_t ws_size,
                              hipStream_t stream) {
    const float* x = (const float*)d_in[0];
    const int* ei = (const int*)d_in[1];   // [2][E]: src row then dst row
    const int* et = (const int*)d_in[2];   // [E]
    const float* W1 = (const float*)d_in[3];    // [2][128][64]
    const float* root1 = (const float*)d_in[4]; // [128][64]
    const float* b1 = (const float*)d_in[5];
    const float* g1 = (const float*)d_in[6];
    const float* beta1 = (const float*)d_in[7];
    const float* W2 = (const float*)d_in[8];    // [2][64][64]
    const float* root2 = (const float*)d_in[9]; // [64][64]
    const float* b2 = (const float*)d_in[10];
    const float* g2 = (const float*)d_in[11];
    const float* beta2 = (const float*)d_in[12];

    const int E = in_sizes[2];
    const int N = in_sizes[0] / IN_DIM;
    const int nseg = NREL * N;

    const int WF1 = 12 * 4 * 2 * 512;  // 49152 shorts
    const int WF2 = 12 * 2 * 2 * 512;  // 24576 shorts

    // workspace layout: W fragment packs first (16B-aligned), floats, ints
    short* Wf1 = (short*)d_ws;
    short* Wf2 = Wf1 + WF1;
    float* PA = (float*)(Wf2 + WF2);
    float* PB = PA + (size_t)N * 64;
    float* PR = PB + (size_t)N * 64;
    float* H  = PR + (size_t)N * 64;
    int* cnt    = (int*)(H + (size_t)N * 64);
    int* excl   = cnt + nseg;
    int* rowptr = excl + nseg;          // nseg + 1
    int* cursor = rowptr + nseg + 1;
    int* colA   = cursor + nseg;        // E
    int* bsum   = colA + E;             // 256
    int* boff   = bsum + 256;           // 256

    const int* esrc = ei;
    const int* edst = ei + E;

    // ---- CSR build ----
    zero_ints<<<(nseg + 255) / 256, 256, 0, stream>>>(cnt, nseg);
    count_edges<<<(E + 255) / 256, 256, 0, stream>>>(et, edst, cnt, E, N);
    int nb = (nseg + SCAN_T * SCAN_I - 1) / (SCAN_T * SCAN_I);
    scan_phase1<<<nb, SCAN_T, 0, stream>>>(cnt, excl, bsum, nseg);
    scan_phase1<<<1, SCAN_T, 0, stream>>>(bsum, boff, nullptr, nb);
    scan_phase3<<<(nseg + 255) / 256, 256, 0, stream>>>(excl, boff, rowptr, cursor,
                                                        nseg, E);
    fill_edges<<<(E + 255) / 256, 256, 0, stream>>>(et, esrc, edst, cursor, colA, E, N);

    // ---- W repack (both layers, fragment order, hi/lo split) ----
    repack_w_frag<<<(WF1 + WF2 + 255) / 256, 256, 0, stream>>>(
        W1, root1, W2, root2, Wf1, Wf2);

    // ---- Layer 1 ----
    int gblocks = (N + 63) / 64;
    gemm_mfma<IN_DIM><<<gblocks, 256, 0, stream>>>(x, Wf1, PA, PB, PR, N);
    agg_ln_kernel<<<(N + 3) / 4, 256, 0, stream>>>(PA, PB, PR, rowptr, colA, b1, g1,
                                                   beta1, H, N, 1);

    // ---- Layer 2 ----
    gemm_mfma<HID><<<gblocks, 256, 0, stream>>>(H, Wf2, PA, PB, PR, N);
    agg_ln_kernel<<<(N + 3) / 4, 256, 0, stream>>>(PA, PB, PR, rowptr, colA, b2, g2,
                                                   beta2, (float*)d_out, N, 0);
}

// Round 6
// 298.419 us; speedup vs baseline: 1.9973x; 1.0965x over previous
//
#include <hip/hip_runtime.h>
#include <hip/hip_bf16.h>
#include <math.h>

#define IN_DIM 128
#define HID 64
#define NREL 2

using f32x4 = __attribute__((ext_vector_type(4))) float;
using s16x8 = __attribute__((ext_vector_type(8))) short;

// fp32 -> bf16 (RNE) and back, via bit ops
__device__ __forceinline__ short f2bf(float f) {
    unsigned u = __float_as_uint(f);
    unsigned r = (u + 0x7fffu + ((u >> 16) & 1u)) >> 16;
    return (short)r;
}
__device__ __forceinline__ float bf2f(short b) {
    return __uint_as_float(((unsigned)(unsigned short)b) << 16);
}

// ---------------------------------------------------------------------------
// Utility: zero an int array
// ---------------------------------------------------------------------------
__global__ void zero_ints(int* p, int n) {
    int i = blockIdx.x * blockDim.x + threadIdx.x;
    if (i < n) p[i] = 0;
}

// ---------------------------------------------------------------------------
// CSR build: count edges per (rel, dst)
// ---------------------------------------------------------------------------
__global__ void count_edges(const int* __restrict__ et, const int* __restrict__ dst,
                            int* __restrict__ cnt, int E, int N) {
    int e = blockIdx.x * blockDim.x + threadIdx.x;
    if (e < E) {
        atomicAdd(&cnt[et[e] * N + dst[e]], 1);
    }
}

// ---------------------------------------------------------------------------
// Scan phase 1: per-block (1024 elems) exclusive scan + block sums
// ---------------------------------------------------------------------------
#define SCAN_T 256
#define SCAN_I 4
__global__ void scan_phase1(const int* __restrict__ in, int* __restrict__ excl,
                            int* __restrict__ bsum, int n) {
    __shared__ int sdata[SCAN_T];
    int b = blockIdx.x;
    int t = threadIdx.x;
    int base = b * SCAN_T * SCAN_I;
    int v[SCAN_I];
    int s = 0;
#pragma unroll
    for (int i = 0; i < SCAN_I; ++i) {
        int idx = base + t * SCAN_I + i;
        v[i] = (idx < n) ? in[idx] : 0;
        s += v[i];
    }
    sdata[t] = s;
    __syncthreads();
    for (int off = 1; off < SCAN_T; off <<= 1) {
        int x = (t >= off) ? sdata[t - off] : 0;
        __syncthreads();
        sdata[t] += x;
        __syncthreads();
    }
    int run = sdata[t] - s;
    if (bsum && t == SCAN_T - 1) bsum[b] = sdata[SCAN_T - 1];
#pragma unroll
    for (int i = 0; i < SCAN_I; ++i) {
        int idx = base + t * SCAN_I + i;
        if (idx < n) excl[idx] = run;
        run += v[i];
    }
}

// ---------------------------------------------------------------------------
// Scan phase 3: add block offsets, produce rowptr and cursor copies
// ---------------------------------------------------------------------------
__global__ void scan_phase3(const int* __restrict__ excl, const int* __restrict__ boff,
                            int* __restrict__ rowptr, int* __restrict__ cursor,
                            int n, int total) {
    int i = blockIdx.x * blockDim.x + threadIdx.x;
    if (i < n) {
        int v = excl[i] + boff[i / (SCAN_T * SCAN_I)];
        rowptr[i] = v;
        cursor[i] = v;
    }
    if (i == 0) rowptr[n] = total;
}

// ---------------------------------------------------------------------------
// CSR fill: scatter src indices into relation/dst-grouped slots
// ---------------------------------------------------------------------------
__global__ void fill_edges(const int* __restrict__ et, const int* __restrict__ src,
                           const int* __restrict__ dst, int* __restrict__ cursor,
                           int* __restrict__ col, int E, int N) {
    int e = blockIdx.x * blockDim.x + threadIdx.x;
    if (e < E) {
        int slot = atomicAdd(&cursor[et[e] * N + dst[e]], 1);
        col[slot] = src[e];
    }
}

// ---------------------------------------------------------------------------
// W repack into MFMA B-fragment order, split hi/lo bf16. (unchanged)
// ---------------------------------------------------------------------------
__device__ __forceinline__ void repack_one(const float* Wa, const float* Wb,
                                           const float* Wr, short* Wf, int T,
                                           int idx) {
    int g = idx >> 9;
    int r = idx & 511;
    int lane = r >> 3;
    int j = r & 7;
    int part = g & 1;
    int ct = g >> 1;
    int t = ct % T;
    int c = ct / T;
    int col = c * 16 + (lane & 15);
    int k = t * 32 + ((lane >> 4) << 3) + j;
    const float* Wg = (col < 64) ? Wa : (col < 128) ? Wb : Wr;
    float v = Wg[(size_t)k * 64 + (col & 63)];
    short hi = f2bf(v);
    Wf[idx] = part ? f2bf(v - bf2f(hi)) : hi;
}

__global__ void repack_w_frag(const float* __restrict__ W1,
                              const float* __restrict__ root1,
                              const float* __restrict__ W2,
                              const float* __restrict__ root2,
                              short* __restrict__ Wf1, short* __restrict__ Wf2) {
    const int L1 = 12 * 4 * 2 * 512;  // 49152
    const int L2 = 12 * 2 * 2 * 512;  // 24576
    int tid = blockIdx.x * blockDim.x + threadIdx.x;
    if (tid < L1) {
        repack_one(W1, W1 + (size_t)IN_DIM * 64, root1, Wf1, 4, tid);
    } else if (tid < L1 + L2) {
        repack_one(W2, W2 + (size_t)HID * 64, root2, Wf2, 2, tid - L1);
    }
}

// ---------------------------------------------------------------------------
// Split-bf16 MFMA GEMM v2: latency-oriented restructure.
// - All T*2 X dwordx4 loads issued up-front (deep VMEM queue), split to
//   bf16 hi/lo once, reused across col-tiles.
// - 12 col-tiles split 6/6 across wave pairs sharing the same 16 rows
//   (2nd wave's X loads L1-hit; 2x wave count, half per-wave L2 volume).
// - Wf fragment loads double-buffered across col-tiles, static reg indices.
// Block 256 = 4 waves = 2 row-tiles x 2 col-halves = 32 rows.
// ---------------------------------------------------------------------------
template <int K>
__global__ __launch_bounds__(256) void gemm_mfma(
    const float* __restrict__ X, const short* __restrict__ Wf,
    float* __restrict__ PA, float* __restrict__ PB, float* __restrict__ PR,
    int M) {
    constexpr int T = K / 32;
    const int lane = threadIdx.x & 63;
    const int wid = threadIdx.x >> 6;
    const int row0 = blockIdx.x * 32 + (wid >> 1) * 16;
    const int cbase = (wid & 1) * 6;

    int arow = row0 + (lane & 15);
    if (arow > M - 1) arow = M - 1;
    const float* xr = X + (size_t)arow * K + ((lane >> 4) << 3);
    const s16x8* WfV = (const s16x8*)Wf;

    // ---- all X loads up-front ----
    float4 xa[T][2];
#pragma unroll
    for (int t = 0; t < T; ++t) {
        xa[t][0] = *reinterpret_cast<const float4*>(xr + t * 32);
        xa[t][1] = *reinterpret_cast<const float4*>(xr + t * 32 + 4);
    }
    // ---- split once ----
    s16x8 ah[T], al[T];
#pragma unroll
    for (int t = 0; t < T; ++t) {
        const float av[8] = {xa[t][0].x, xa[t][0].y, xa[t][0].z, xa[t][0].w,
                             xa[t][1].x, xa[t][1].y, xa[t][1].z, xa[t][1].w};
#pragma unroll
        for (int j = 0; j < 8; ++j) {
            short h = f2bf(av[j]);
            ah[t][j] = h;
            al[t][j] = f2bf(av[j] - bf2f(h));
        }
    }

    f32x4 acc[6];
#pragma unroll
    for (int c = 0; c < 6; ++c) acc[c] = (f32x4){0.f, 0.f, 0.f, 0.f};

    s16x8 bhA[T], blA[T], bhB[T], blB[T];

#define LOADB(H, L, CG)                                                       \
    {                                                                         \
        _Pragma("unroll") for (int t = 0; t < T; ++t) {                       \
            H[t] = WfV[(size_t)(((CG) * T + t) * 2 + 0) * 64 + lane];         \
            L[t] = WfV[(size_t)(((CG) * T + t) * 2 + 1) * 64 + lane];         \
        }                                                                     \
    }
#define DOMFMA(H, L, CI)                                                      \
    {                                                                         \
        _Pragma("unroll") for (int t = 0; t < T; ++t) {                       \
            acc[CI] = __builtin_amdgcn_mfma_f32_16x16x32_bf16(ah[t], H[t],    \
                                                              acc[CI], 0, 0, 0); \
            acc[CI] = __builtin_amdgcn_mfma_f32_16x16x32_bf16(al[t], H[t],    \
                                                              acc[CI], 0, 0, 0); \
            acc[CI] = __builtin_amdgcn_mfma_f32_16x16x32_bf16(ah[t], L[t],    \
                                                              acc[CI], 0, 0, 0); \
        }                                                                     \
    }

    LOADB(bhA, blA, cbase + 0);
    LOADB(bhB, blB, cbase + 1);
    DOMFMA(bhA, blA, 0);
    LOADB(bhA, blA, cbase + 2);
    DOMFMA(bhB, blB, 1);
    LOADB(bhB, blB, cbase + 3);
    DOMFMA(bhA, blA, 2);
    LOADB(bhA, blA, cbase + 4);
    DOMFMA(bhB, blB, 3);
    LOADB(bhB, blB, cbase + 5);
    DOMFMA(bhA, blA, 4);
    DOMFMA(bhB, blB, 5);

#undef LOADB
#undef DOMFMA

    const int drow = row0 + ((lane >> 4) << 2);
    const int dcol = lane & 15;
#pragma unroll
    for (int ci = 0; ci < 6; ++ci) {
        const int cg = cbase + ci;
        float* base = (cg < 4) ? PA : (cg < 8) ? PB : PR;
        const int cc = (cg & 3) * 16 + dcol;
#pragma unroll
        for (int q = 0; q < 4; ++q) {
            const int row = drow + q;
            if (row < M) base[(size_t)row * 64 + cc] = acc[ci][q];
        }
    }
}

// ---------------------------------------------------------------------------
// Aggregate + LayerNorm (+ optional exact GELU), 4-edge-parallel gather.
// (unchanged)
// ---------------------------------------------------------------------------
__device__ __forceinline__ float4 shfl_xor_f4(float4 v, int m) {
    return make_float4(__shfl_xor(v.x, m), __shfl_xor(v.y, m),
                       __shfl_xor(v.z, m), __shfl_xor(v.w, m));
}

__global__ __launch_bounds__(256) void agg_ln_kernel(
    const float* __restrict__ PA, const float* __restrict__ PB,
    const float* __restrict__ PR,
    const int* __restrict__ rowptr, const int* __restrict__ col,
    const float* __restrict__ bias, const float* __restrict__ g,
    const float* __restrict__ beta,
    float* __restrict__ out, int N, int gelu) {
    const int t = threadIdx.x;
    const int lane = t & 63;
    const int sub = lane >> 4;   // which edge within a quad
    const int c = lane & 15;     // feature quad index
    const int node = blockIdx.x * 4 + (t >> 6);
    if (node >= N) return;

    float4 acc = *reinterpret_cast<const float4*>(PR + (size_t)node * 64 + c * 4);
    {
        float4 b4 = *reinterpret_cast<const float4*>(bias + c * 4);
        acc.x += b4.x; acc.y += b4.y; acc.z += b4.z; acc.w += b4.w;
    }

#pragma unroll
    for (int r = 0; r < 2; ++r) {
        const float* __restrict__ P = r ? PB : PA;
        const int beg = rowptr[r * N + node];
        const int end = rowptr[r * N + node + 1];
        float4 s0 = make_float4(0.f, 0.f, 0.f, 0.f);
        float4 s1 = make_float4(0.f, 0.f, 0.f, 0.f);
        for (int i = beg + sub; i < end; i += 8) {
            const float4 v0 =
                *reinterpret_cast<const float4*>(P + (size_t)col[i] * 64 + c * 4);
            s0.x += v0.x; s0.y += v0.y; s0.z += v0.z; s0.w += v0.w;
            const int j = i + 4;
            if (j < end) {
                const float4 v1 =
                    *reinterpret_cast<const float4*>(P + (size_t)col[j] * 64 + c * 4);
                s1.x += v1.x; s1.y += v1.y; s1.z += v1.z; s1.w += v1.w;
            }
        }
        s0.x += s1.x; s0.y += s1.y; s0.z += s1.z; s0.w += s1.w;
        float4 o = shfl_xor_f4(s0, 16);
        s0.x += o.x; s0.y += o.y; s0.z += o.z; s0.w += o.w;
        o = shfl_xor_f4(s0, 32);
        s0.x += o.x; s0.y += o.y; s0.z += o.z; s0.w += o.w;
        const int deg = end - beg;
        if (deg > 0) {
            const float inv = 1.f / (float)deg;
            acc.x += s0.x * inv; acc.y += s0.y * inv;
            acc.z += s0.z * inv; acc.w += s0.w * inv;
        }
    }

    // LayerNorm over 64 features (16 lanes x float4; groups replicated x4)
    float ps = acc.x + acc.y + acc.z + acc.w;
#pragma unroll
    for (int off = 1; off <= 8; off <<= 1) ps += __shfl_xor(ps, off);
    const float mu = ps * (1.f / 64.f);
    const float4 d = make_float4(acc.x - mu, acc.y - mu, acc.z - mu, acc.w - mu);
    float vs = d.x * d.x + d.y * d.y + d.z * d.z + d.w * d.w;
#pragma unroll
    for (int off = 1; off <= 8; off <<= 1) vs += __shfl_xor(vs, off);
    const float rstd = 1.f / sqrtf(vs * (1.f / 64.f) + 1e-5f);

    const float4 g4 = *reinterpret_cast<const float4*>(g + c * 4);
    const float4 be4 = *reinterpret_cast<const float4*>(beta + c * 4);
    float4 y;
    y.x = d.x * rstd * g4.x + be4.x;
    y.y = d.y * rstd * g4.y + be4.y;
    y.z = d.z * rstd * g4.z + be4.z;
    y.w = d.w * rstd * g4.w + be4.w;

    if (gelu) {
        y.x = 0.5f * y.x * (1.f + erff(y.x * 0.70710678118654752440f));
        y.y = 0.5f * y.y * (1.f + erff(y.y * 0.70710678118654752440f));
        y.z = 0.5f * y.z * (1.f + erff(y.z * 0.70710678118654752440f));
        y.w = 0.5f * y.w * (1.f + erff(y.w * 0.70710678118654752440f));
    }

    if (sub == 0)
        *reinterpret_cast<float4*>(out + (size_t)node * 64 + c * 4) = y;
}

// ---------------------------------------------------------------------------
// Launch
// ---------------------------------------------------------------------------
extern "C" void kernel_launch(void* const* d_in, const int* in_sizes, int n_in,
                              void* d_out, int out_size, void* d_ws, size_t ws_size,
                              hipStream_t stream) {
    const float* x = (const float*)d_in[0];
    const int* ei = (const int*)d_in[1];   // [2][E]: src row then dst row
    const int* et = (const int*)d_in[2];   // [E]
    const float* W1 = (const float*)d_in[3];    // [2][128][64]
    const float* root1 = (const float*)d_in[4]; // [128][64]
    const float* b1 = (const float*)d_in[5];
    const float* g1 = (const float*)d_in[6];
    const float* beta1 = (const float*)d_in[7];
    const float* W2 = (const float*)d_in[8];    // [2][64][64]
    const float* root2 = (const float*)d_in[9]; // [64][64]
    const float* b2 = (const float*)d_in[10];
    const float* g2 = (const float*)d_in[11];
    const float* beta2 = (const float*)d_in[12];

    const int E = in_sizes[2];
    const int N = in_sizes[0] / IN_DIM;
    const int nseg = NREL * N;

    const int WF1 = 12 * 4 * 2 * 512;  // 49152 shorts
    const int WF2 = 12 * 2 * 2 * 512;  // 24576 shorts

    // workspace layout: W fragment packs first (16B-aligned), floats, ints
    short* Wf1 = (short*)d_ws;
    short* Wf2 = Wf1 + WF1;
    float* PA = (float*)(Wf2 + WF2);
    float* PB = PA + (size_t)N * 64;
    float* PR = PB + (size_t)N * 64;
    float* H  = PR + (size_t)N * 64;
    int* cnt    = (int*)(H + (size_t)N * 64);
    int* excl   = cnt + nseg;
    int* rowptr = excl + nseg;          // nseg + 1
    int* cursor = rowptr + nseg + 1;
    int* colA   = cursor + nseg;        // E
    int* bsum   = colA + E;             // 256
    int* boff   = bsum + 256;           // 256

    const int* esrc = ei;
    const int* edst = ei + E;

    // ---- CSR build ----
    zero_ints<<<(nseg + 255) / 256, 256, 0, stream>>>(cnt, nseg);
    count_edges<<<(E + 255) / 256, 256, 0, stream>>>(et, edst, cnt, E, N);
    int nb = (nseg + SCAN_T * SCAN_I - 1) / (SCAN_T * SCAN_I);
    scan_phase1<<<nb, SCAN_T, 0, stream>>>(cnt, excl, bsum, nseg);
    scan_phase1<<<1, SCAN_T, 0, stream>>>(bsum, boff, nullptr, nb);
    scan_phase3<<<(nseg + 255) / 256, 256, 0, stream>>>(excl, boff, rowptr, cursor,
                                                        nseg, E);
    fill_edges<<<(E + 255) / 256, 256, 0, stream>>>(et, esrc, edst, cursor, colA, E, N);

    // ---- W repack (both layers, fragment order, hi/lo split) ----
    repack_w_frag<<<(WF1 + WF2 + 255) / 256, 256, 0, stream>>>(
        W1, root1, W2, root2, Wf1, Wf2);

    // ---- Layer 1 ----
    int gblocks = (N + 31) / 32;
    gemm_mfma<IN_DIM><<<gblocks, 256, 0, stream>>>(x, Wf1, PA, PB, PR, N);
    agg_ln_kernel<<<(N + 3) / 4, 256, 0, stream>>>(PA, PB, PR, rowptr, colA, b1, g1,
                                                   beta1, H, N, 1);

    // ---- Layer 2 ----
    gemm_mfma<HID><<<gblocks, 256, 0, stream>>>(H, Wf2, PA, PB, PR, N);
    agg_ln_kernel<<<(N + 3) / 4, 256, 0, stream>>>(PA, PB, PR, rowptr, colA, b2, g2,
                                                   beta2, (float*)d_out, N, 0);
}

// Round 7
// 290.270 us; speedup vs baseline: 2.0534x; 1.0281x over previous
//
#include <hip/hip_runtime.h>
#include <hip/hip_bf16.h>
#include <math.h>

#define IN_DIM 128
#define HID 64
#define NREL 2

using f32x4 = __attribute__((ext_vector_type(4))) float;
using s16x8 = __attribute__((ext_vector_type(8))) short;

// fp32 -> bf16 (RNE) and back, via bit ops
__device__ __forceinline__ short f2bf(float f) {
    unsigned u = __float_as_uint(f);
    unsigned r = (u + 0x7fffu + ((u >> 16) & 1u)) >> 16;
    return (short)r;
}
__device__ __forceinline__ float bf2f(short b) {
    return __uint_as_float(((unsigned)(unsigned short)b) << 16);
}

// ---------------------------------------------------------------------------
// Utility: zero an int array
// ---------------------------------------------------------------------------
__global__ void zero_ints(int* p, int n) {
    int i = blockIdx.x * blockDim.x + threadIdx.x;
    if (i < n) p[i] = 0;
}

// ---------------------------------------------------------------------------
// CSR build: count edges per (rel, dst)  [2N buckets, for per-rel inv-deg]
// ---------------------------------------------------------------------------
__global__ void count_edges(const int* __restrict__ et, const int* __restrict__ dst,
                            int* __restrict__ cnt, int E, int N) {
    int e = blockIdx.x * blockDim.x + threadIdx.x;
    if (e < E) {
        atomicAdd(&cnt[et[e] * N + dst[e]], 1);
    }
}

// ---------------------------------------------------------------------------
// Scan phase 1: per-block (1024 elems) exclusive scan + block sums.
// If in2 != null, scans in[i] + in2[i] (paired sum, dst-total degree).
// ---------------------------------------------------------------------------
#define SCAN_T 256
#define SCAN_I 4
__global__ void scan_phase1(const int* __restrict__ in, const int* __restrict__ in2,
                            int* __restrict__ excl, int* __restrict__ bsum, int n) {
    __shared__ int sdata[SCAN_T];
    int b = blockIdx.x;
    int t = threadIdx.x;
    int base = b * SCAN_T * SCAN_I;
    int v[SCAN_I];
    int s = 0;
#pragma unroll
    for (int i = 0; i < SCAN_I; ++i) {
        int idx = base + t * SCAN_I + i;
        v[i] = (idx < n) ? (in2 ? in[idx] + in2[idx] : in[idx]) : 0;
        s += v[i];
    }
    sdata[t] = s;
    __syncthreads();
    for (int off = 1; off < SCAN_T; off <<= 1) {
        int x = (t >= off) ? sdata[t - off] : 0;
        __syncthreads();
        sdata[t] += x;
        __syncthreads();
    }
    int run = sdata[t] - s;
    if (bsum && t == SCAN_T - 1) bsum[b] = sdata[SCAN_T - 1];
#pragma unroll
    for (int i = 0; i < SCAN_I; ++i) {
        int idx = base + t * SCAN_I + i;
        if (idx < n) excl[idx] = run;
        run += v[i];
    }
}

// ---------------------------------------------------------------------------
// Scan phase 3: add block offsets, produce rowptr and cursor copies
// ---------------------------------------------------------------------------
__global__ void scan_phase3(const int* __restrict__ excl, const int* __restrict__ boff,
                            int* __restrict__ rowptr, int* __restrict__ cursor,
                            int n, int total) {
    int i = blockIdx.x * blockDim.x + threadIdx.x;
    if (i < n) {
        int v = excl[i] + boff[i / (SCAN_T * SCAN_I)];
        rowptr[i] = v;
        cursor[i] = v;
    }
    if (i == 0) rowptr[n] = total;
}

// ---------------------------------------------------------------------------
// CSR fill v2: dst-grouped slots; payload packs {row = rel*N+src, 1/deg_rel}
// into one 8B agent-scope (write-through, no L2 line allocate -> no XCD
// line bounce) store. Gather side then needs no per-rel bookkeeping at all.
// ---------------------------------------------------------------------------
__global__ void fill_edges(const int* __restrict__ et, const int* __restrict__ src,
                           const int* __restrict__ dst, const int* __restrict__ cnt2,
                           int* __restrict__ cursor, int2* __restrict__ colw,
                           int E, int N) {
    int e = blockIdx.x * blockDim.x + threadIdx.x;
    if (e < E) {
        int d = dst[e];
        int r = et[e];
        int s = src[e];
        int slot = atomicAdd(&cursor[d], 1);
        int deg = cnt2[r * N + d];            // >= 1 (this edge exists)
        float iw = 1.f / (float)deg;
        unsigned long long v = (unsigned long long)(unsigned)(r * N + s) |
                               ((unsigned long long)__float_as_uint(iw) << 32);
        __hip_atomic_store((unsigned long long*)(colw + slot), v,
                           __ATOMIC_RELAXED, __HIP_MEMORY_SCOPE_AGENT);
    }
}

// ---------------------------------------------------------------------------
// W repack into MFMA B-fragment order, split hi/lo bf16. (unchanged)
// ---------------------------------------------------------------------------
__device__ __forceinline__ void repack_one(const float* Wa, const float* Wb,
                                           const float* Wr, short* Wf, int T,
                                           int idx) {
    int g = idx >> 9;
    int r = idx & 511;
    int lane = r >> 3;
    int j = r & 7;
    int part = g & 1;
    int ct = g >> 1;
    int t = ct % T;
    int c = ct / T;
    int col = c * 16 + (lane & 15);
    int k = t * 32 + ((lane >> 4) << 3) + j;
    const float* Wg = (col < 64) ? Wa : (col < 128) ? Wb : Wr;
    float v = Wg[(size_t)k * 64 + (col & 63)];
    short hi = f2bf(v);
    Wf[idx] = part ? f2bf(v - bf2f(hi)) : hi;
}

__global__ void repack_w_frag(const float* __restrict__ W1,
                              const float* __restrict__ root1,
                              const float* __restrict__ W2,
                              const float* __restrict__ root2,
                              short* __restrict__ Wf1, short* __restrict__ Wf2) {
    const int L1 = 12 * 4 * 2 * 512;  // 49152
    const int L2 = 12 * 2 * 2 * 512;  // 24576
    int tid = blockIdx.x * blockDim.x + threadIdx.x;
    if (tid < L1) {
        repack_one(W1, W1 + (size_t)IN_DIM * 64, root1, Wf1, 4, tid);
    } else if (tid < L1 + L2) {
        repack_one(W2, W2 + (size_t)HID * 64, root2, Wf2, 2, tid - L1);
    }
}

// ---------------------------------------------------------------------------
// Split-bf16 MFMA GEMM v2 (unchanged from R6).
// ---------------------------------------------------------------------------
template <int K>
__global__ __launch_bounds__(256) void gemm_mfma(
    const float* __restrict__ X, const short* __restrict__ Wf,
    float* __restrict__ PA, float* __restrict__ PB, float* __restrict__ PR,
    int M) {
    constexpr int T = K / 32;
    const int lane = threadIdx.x & 63;
    const int wid = threadIdx.x >> 6;
    const int row0 = blockIdx.x * 32 + (wid >> 1) * 16;
    const int cbase = (wid & 1) * 6;

    int arow = row0 + (lane & 15);
    if (arow > M - 1) arow = M - 1;
    const float* xr = X + (size_t)arow * K + ((lane >> 4) << 3);
    const s16x8* WfV = (const s16x8*)Wf;

    float4 xa[T][2];
#pragma unroll
    for (int t = 0; t < T; ++t) {
        xa[t][0] = *reinterpret_cast<const float4*>(xr + t * 32);
        xa[t][1] = *reinterpret_cast<const float4*>(xr + t * 32 + 4);
    }
    s16x8 ah[T], al[T];
#pragma unroll
    for (int t = 0; t < T; ++t) {
        const float av[8] = {xa[t][0].x, xa[t][0].y, xa[t][0].z, xa[t][0].w,
                             xa[t][1].x, xa[t][1].y, xa[t][1].z, xa[t][1].w};
#pragma unroll
        for (int j = 0; j < 8; ++j) {
            short h = f2bf(av[j]);
            ah[t][j] = h;
            al[t][j] = f2bf(av[j] - bf2f(h));
        }
    }

    f32x4 acc[6];
#pragma unroll
    for (int c = 0; c < 6; ++c) acc[c] = (f32x4){0.f, 0.f, 0.f, 0.f};

    s16x8 bhA[T], blA[T], bhB[T], blB[T];

#define LOADB(H, L, CG)                                                       \
    {                                                                         \
        _Pragma("unroll") for (int t = 0; t < T; ++t) {                       \
            H[t] = WfV[(size_t)(((CG) * T + t) * 2 + 0) * 64 + lane];         \
            L[t] = WfV[(size_t)(((CG) * T + t) * 2 + 1) * 64 + lane];         \
        }                                                                     \
    }
#define DOMFMA(H, L, CI)                                                      \
    {                                                                         \
        _Pragma("unroll") for (int t = 0; t < T; ++t) {                       \
            acc[CI] = __builtin_amdgcn_mfma_f32_16x16x32_bf16(ah[t], H[t],    \
                                                              acc[CI], 0, 0, 0); \
            acc[CI] = __builtin_amdgcn_mfma_f32_16x16x32_bf16(al[t], H[t],    \
                                                              acc[CI], 0, 0, 0); \
            acc[CI] = __builtin_amdgcn_mfma_f32_16x16x32_bf16(ah[t], L[t],    \
                                                              acc[CI], 0, 0, 0); \
        }                                                                     \
    }

    LOADB(bhA, blA, cbase + 0);
    LOADB(bhB, blB, cbase + 1);
    DOMFMA(bhA, blA, 0);
    LOADB(bhA, blA, cbase + 2);
    DOMFMA(bhB, blB, 1);
    LOADB(bhB, blB, cbase + 3);
    DOMFMA(bhA, blA, 2);
    LOADB(bhA, blA, cbase + 4);
    DOMFMA(bhB, blB, 3);
    LOADB(bhB, blB, cbase + 5);
    DOMFMA(bhA, blA, 4);
    DOMFMA(bhB, blB, 5);

#undef LOADB
#undef DOMFMA

    const int drow = row0 + ((lane >> 4) << 2);
    const int dcol = lane & 15;
#pragma unroll
    for (int ci = 0; ci < 6; ++ci) {
        const int cg = cbase + ci;
        float* base = (cg < 4) ? PA : (cg < 8) ? PB : PR;
        const int cc = (cg & 3) * 16 + dcol;
#pragma unroll
        for (int q = 0; q < 4; ++q) {
            const int row = drow + q;
            if (row < M) base[(size_t)row * 64 + cc] = acc[ci][q];
        }
    }
}

// ---------------------------------------------------------------------------
// Aggregate + LayerNorm (+ optional exact GELU), v3: single fused edge loop.
// CSR is dst-grouped; colw[slot] = {row = rel*N+src, 1/deg_rel} so the
// per-relation mean is a per-edge FMA scale into ONE accumulator. Wave =
// 1 node, 4 sub-groups x 16 lanes, 4 staggered loads per iteration
// (16 rows in flight per wave; avg total deg 16 -> ~1 iteration).
// ---------------------------------------------------------------------------
__device__ __forceinline__ float4 shfl_xor_f4(float4 v, int m) {
    return make_float4(__shfl_xor(v.x, m), __shfl_xor(v.y, m),
                       __shfl_xor(v.z, m), __shfl_xor(v.w, m));
}

__global__ __launch_bounds__(256) void agg_ln_kernel(
    const float* __restrict__ Pcat,   // [2N,64] = PA|PB
    const float* __restrict__ PR,
    const int* __restrict__ rowptr,   // [N+1], dst-grouped
    const int2* __restrict__ colw,    // [E] {row, invdeg bits}
    const float* __restrict__ bias, const float* __restrict__ g,
    const float* __restrict__ beta,
    float* __restrict__ out, int N, int gelu) {
    const int t = threadIdx.x;
    const int lane = t & 63;
    const int sub = lane >> 4;
    const int c = lane & 15;
    const int node = blockIdx.x * 4 + (t >> 6);
    if (node >= N) return;

    const int c4 = c * 4;
    float4 acc = *reinterpret_cast<const float4*>(PR + (size_t)node * 64 + c4);
    {
        float4 b4 = *reinterpret_cast<const float4*>(bias + c4);
        acc.x += b4.x; acc.y += b4.y; acc.z += b4.z; acc.w += b4.w;
    }

    const int beg = rowptr[node];
    const int end = rowptr[node + 1];
    float4 s0 = make_float4(0.f, 0.f, 0.f, 0.f);
    float4 s1 = s0, s2 = s0, s3 = s0;
    for (int i = beg + sub; i < end; i += 16) {
        {
            const int2 w = colw[i];
            const float4 v = *reinterpret_cast<const float4*>(Pcat + w.x * 64 + c4);
            const float f = __int_as_float(w.y);
            s0.x = fmaf(v.x, f, s0.x); s0.y = fmaf(v.y, f, s0.y);
            s0.z = fmaf(v.z, f, s0.z); s0.w = fmaf(v.w, f, s0.w);
        }
        int j = i + 4;
        if (j < end) {
            const int2 w = colw[j];
            const float4 v = *reinterpret_cast<const float4*>(Pcat + w.x * 64 + c4);
            const float f = __int_as_float(w.y);
            s1.x = fmaf(v.x, f, s1.x); s1.y = fmaf(v.y, f, s1.y);
            s1.z = fmaf(v.z, f, s1.z); s1.w = fmaf(v.w, f, s1.w);
        }
        j = i + 8;
        if (j < end) {
            const int2 w = colw[j];
            const float4 v = *reinterpret_cast<const float4*>(Pcat + w.x * 64 + c4);
            const float f = __int_as_float(w.y);
            s2.x = fmaf(v.x, f, s2.x); s2.y = fmaf(v.y, f, s2.y);
            s2.z = fmaf(v.z, f, s2.z); s2.w = fmaf(v.w, f, s2.w);
        }
        j = i + 12;
        if (j < end) {
            const int2 w = colw[j];
            const float4 v = *reinterpret_cast<const float4*>(Pcat + w.x * 64 + c4);
            const float f = __int_as_float(w.y);
            s3.x = fmaf(v.x, f, s3.x); s3.y = fmaf(v.y, f, s3.y);
            s3.z = fmaf(v.z, f, s3.z); s3.w = fmaf(v.w, f, s3.w);
        }
    }
    s0.x += s1.x + s2.x + s3.x;
    s0.y += s1.y + s2.y + s3.y;
    s0.z += s1.z + s2.z + s3.z;
    s0.w += s1.w + s2.w + s3.w;
    float4 o = shfl_xor_f4(s0, 16);
    s0.x += o.x; s0.y += o.y; s0.z += o.z; s0.w += o.w;
    o = shfl_xor_f4(s0, 32);
    s0.x += o.x; s0.y += o.y; s0.z += o.z; s0.w += o.w;
    acc.x += s0.x; acc.y += s0.y; acc.z += s0.z; acc.w += s0.w;

    // LayerNorm over 64 features (16 lanes x float4; replicated x4 subs)
    float ps = acc.x + acc.y + acc.z + acc.w;
#pragma unroll
    for (int off = 1; off <= 8; off <<= 1) ps += __shfl_xor(ps, off);
    const float mu = ps * (1.f / 64.f);
    const float4 d = make_float4(acc.x - mu, acc.y - mu, acc.z - mu, acc.w - mu);
    float vs = d.x * d.x + d.y * d.y + d.z * d.z + d.w * d.w;
#pragma unroll
    for (int off = 1; off <= 8; off <<= 1) vs += __shfl_xor(vs, off);
    const float rstd = 1.f / sqrtf(vs * (1.f / 64.f) + 1e-5f);

    const float4 g4 = *reinterpret_cast<const float4*>(g + c4);
    const float4 be4 = *reinterpret_cast<const float4*>(beta + c4);
    float4 y;
    y.x = d.x * rstd * g4.x + be4.x;
    y.y = d.y * rstd * g4.y + be4.y;
    y.z = d.z * rstd * g4.z + be4.z;
    y.w = d.w * rstd * g4.w + be4.w;

    if (gelu) {
        y.x = 0.5f * y.x * (1.f + erff(y.x * 0.70710678118654752440f));
        y.y = 0.5f * y.y * (1.f + erff(y.y * 0.70710678118654752440f));
        y.z = 0.5f * y.z * (1.f + erff(y.z * 0.70710678118654752440f));
        y.w = 0.5f * y.w * (1.f + erff(y.w * 0.70710678118654752440f));
    }

    if (sub == 0)
        *reinterpret_cast<float4*>(out + (size_t)node * 64 + c4) = y;
}

// ---------------------------------------------------------------------------
// Launch
// ---------------------------------------------------------------------------
extern "C" void kernel_launch(void* const* d_in, const int* in_sizes, int n_in,
                              void* d_out, int out_size, void* d_ws, size_t ws_size,
                              hipStream_t stream) {
    const float* x = (const float*)d_in[0];
    const int* ei = (const int*)d_in[1];   // [2][E]: src row then dst row
    const int* et = (const int*)d_in[2];   // [E]
    const float* W1 = (const float*)d_in[3];    // [2][128][64]
    const float* root1 = (const float*)d_in[4]; // [128][64]
    const float* b1 = (const float*)d_in[5];
    const float* g1 = (const float*)d_in[6];
    const float* beta1 = (const float*)d_in[7];
    const float* W2 = (const float*)d_in[8];    // [2][64][64]
    const float* root2 = (const float*)d_in[9]; // [64][64]
    const float* b2 = (const float*)d_in[10];
    const float* g2 = (const float*)d_in[11];
    const float* beta2 = (const float*)d_in[12];

    const int E = in_sizes[2];
    const int N = in_sizes[0] / IN_DIM;

    const int WF1 = 12 * 4 * 2 * 512;  // 49152 shorts
    const int WF2 = 12 * 2 * 2 * 512;  // 24576 shorts

    // workspace layout: Wf packs, float bufs, colw (8B-aligned), int bufs
    short* Wf1 = (short*)d_ws;
    short* Wf2 = Wf1 + WF1;
    float* Pcat = (float*)(Wf2 + WF2);           // [2N,64] = PA|PB
    float* PR   = Pcat + (size_t)2 * N * 64;
    float* H    = PR + (size_t)N * 64;
    int2* colw  = (int2*)(H + (size_t)N * 64);   // E entries, 8B aligned
    int* cnt2   = (int*)(colw + E);              // 2N
    int* excl   = cnt2 + 2 * N;                  // N
    int* rowptr = excl + N;                      // N+1
    int* cursor = rowptr + N + 1;                // N
    int* bsum   = cursor + N;                    // 256
    int* boff   = bsum + 256;                    // 256

    const int* esrc = ei;
    const int* edst = ei + E;

    // ---- CSR build (dst-grouped, per-rel counts for inv-deg) ----
    zero_ints<<<(2 * N + 255) / 256, 256, 0, stream>>>(cnt2, 2 * N);
    count_edges<<<(E + 255) / 256, 256, 0, stream>>>(et, edst, cnt2, E, N);
    int nb = (N + SCAN_T * SCAN_I - 1) / (SCAN_T * SCAN_I);
    scan_phase1<<<nb, SCAN_T, 0, stream>>>(cnt2, cnt2 + N, excl, bsum, N);
    scan_phase1<<<1, SCAN_T, 0, stream>>>(bsum, nullptr, boff, nullptr, nb);
    scan_phase3<<<(N + 255) / 256, 256, 0, stream>>>(excl, boff, rowptr, cursor, N, E);
    fill_edges<<<(E + 255) / 256, 256, 0, stream>>>(et, esrc, edst, cnt2, cursor,
                                                    colw, E, N);

    // ---- W repack (both layers, fragment order, hi/lo split) ----
    repack_w_frag<<<(WF1 + WF2 + 255) / 256, 256, 0, stream>>>(
        W1, root1, W2, root2, Wf1, Wf2);

    // ---- Layer 1 ----
    int gblocks = (N + 31) / 32;
    gemm_mfma<IN_DIM><<<gblocks, 256, 0, stream>>>(
        x, Wf1, Pcat, Pcat + (size_t)N * 64, PR, N);
    agg_ln_kernel<<<(N + 3) / 4, 256, 0, stream>>>(Pcat, PR, rowptr, colw, b1, g1,
                                                   beta1, H, N, 1);

    // ---- Layer 2 ----
    gemm_mfma<HID><<<gblocks, 256, 0, stream>>>(
        H, Wf2, Pcat, Pcat + (size_t)N * 64, PR, N);
    agg_ln_kernel<<<(N + 3) / 4, 256, 0, stream>>>(Pcat, PR, rowptr, colw, b2, g2,
                                                   beta2, (float*)d_out, N, 0);
}

// Round 8
// 289.379 us; speedup vs baseline: 2.0597x; 1.0031x over previous
//
#include <hip/hip_runtime.h>
#include <hip/hip_bf16.h>
#include <math.h>

#define IN_DIM 128
#define HID 64
#define NREL 2

using f32x4 = __attribute__((ext_vector_type(4))) float;
using s16x8 = __attribute__((ext_vector_type(8))) short;

// fp32 -> bf16 (RNE) and back, via bit ops
__device__ __forceinline__ short f2bf(float f) {
    unsigned u = __float_as_uint(f);
    unsigned r = (u + 0x7fffu + ((u >> 16) & 1u)) >> 16;
    return (short)r;
}
__device__ __forceinline__ float bf2f(short b) {
    return __uint_as_float(((unsigned)(unsigned short)b) << 16);
}

// ---------------------------------------------------------------------------
// Utility: zero an int array
// ---------------------------------------------------------------------------
__global__ void zero_ints(int* p, int n) {
    int i = blockIdx.x * blockDim.x + threadIdx.x;
    if (i < n) p[i] = 0;
}

// ---------------------------------------------------------------------------
// CSR build: count edges per (rel, dst)  [2N buckets, for per-rel inv-deg]
// ---------------------------------------------------------------------------
__global__ void count_edges(const int* __restrict__ et, const int* __restrict__ dst,
                            int* __restrict__ cnt, int E, int N) {
    int e = blockIdx.x * blockDim.x + threadIdx.x;
    if (e < E) {
        atomicAdd(&cnt[et[e] * N + dst[e]], 1);
    }
}

// ---------------------------------------------------------------------------
// Scan phase 1: per-block (1024 elems) exclusive scan + block sums.
// If in2 != null, scans in[i] + in2[i] (paired sum, dst-total degree).
// ---------------------------------------------------------------------------
#define SCAN_T 256
#define SCAN_I 4
__global__ void scan_phase1(const int* __restrict__ in, const int* __restrict__ in2,
                            int* __restrict__ excl, int* __restrict__ bsum, int n) {
    __shared__ int sdata[SCAN_T];
    int b = blockIdx.x;
    int t = threadIdx.x;
    int base = b * SCAN_T * SCAN_I;
    int v[SCAN_I];
    int s = 0;
#pragma unroll
    for (int i = 0; i < SCAN_I; ++i) {
        int idx = base + t * SCAN_I + i;
        v[i] = (idx < n) ? (in2 ? in[idx] + in2[idx] : in[idx]) : 0;
        s += v[i];
    }
    sdata[t] = s;
    __syncthreads();
    for (int off = 1; off < SCAN_T; off <<= 1) {
        int x = (t >= off) ? sdata[t - off] : 0;
        __syncthreads();
        sdata[t] += x;
        __syncthreads();
    }
    int run = sdata[t] - s;
    if (bsum && t == SCAN_T - 1) bsum[b] = sdata[SCAN_T - 1];
#pragma unroll
    for (int i = 0; i < SCAN_I; ++i) {
        int idx = base + t * SCAN_I + i;
        if (idx < n) excl[idx] = run;
        run += v[i];
    }
}

// ---------------------------------------------------------------------------
// Scan phase 3: add block offsets, produce rowptr and cursor copies
// ---------------------------------------------------------------------------
__global__ void scan_phase3(const int* __restrict__ excl, const int* __restrict__ boff,
                            int* __restrict__ rowptr, int* __restrict__ cursor,
                            int n, int total) {
    int i = blockIdx.x * blockDim.x + threadIdx.x;
    if (i < n) {
        int v = excl[i] + boff[i / (SCAN_T * SCAN_I)];
        rowptr[i] = v;
        cursor[i] = v;
    }
    if (i == 0) rowptr[n] = total;
}

// ---------------------------------------------------------------------------
// CSR fill: dst-grouped slots; payload packs {row = rel*N+src, 1/deg_rel}
// into one 8B store. (unchanged from R7)
// ---------------------------------------------------------------------------
__global__ void fill_edges(const int* __restrict__ et, const int* __restrict__ src,
                           const int* __restrict__ dst, const int* __restrict__ cnt2,
                           int* __restrict__ cursor, int2* __restrict__ colw,
                           int E, int N) {
    int e = blockIdx.x * blockDim.x + threadIdx.x;
    if (e < E) {
        int d = dst[e];
        int r = et[e];
        int s = src[e];
        int slot = atomicAdd(&cursor[d], 1);
        int deg = cnt2[r * N + d];            // >= 1 (this edge exists)
        float iw = 1.f / (float)deg;
        unsigned long long v = (unsigned long long)(unsigned)(r * N + s) |
                               ((unsigned long long)__float_as_uint(iw) << 32);
        __hip_atomic_store((unsigned long long*)(colw + slot), v,
                           __ATOMIC_RELAXED, __HIP_MEMORY_SCOPE_AGENT);
    }
}

// ---------------------------------------------------------------------------
// W repack into MFMA B-fragment order, split hi/lo bf16. (unchanged)
// ---------------------------------------------------------------------------
__device__ __forceinline__ void repack_one(const float* Wa, const float* Wb,
                                           const float* Wr, short* Wf, int T,
                                           int idx) {
    int g = idx >> 9;
    int r = idx & 511;
    int lane = r >> 3;
    int j = r & 7;
    int part = g & 1;
    int ct = g >> 1;
    int t = ct % T;
    int c = ct / T;
    int col = c * 16 + (lane & 15);
    int k = t * 32 + ((lane >> 4) << 3) + j;
    const float* Wg = (col < 64) ? Wa : (col < 128) ? Wb : Wr;
    float v = Wg[(size_t)k * 64 + (col & 63)];
    short hi = f2bf(v);
    Wf[idx] = part ? f2bf(v - bf2f(hi)) : hi;
}

__global__ void repack_w_frag(const float* __restrict__ W1,
                              const float* __restrict__ root1,
                              const float* __restrict__ W2,
                              const float* __restrict__ root2,
                              short* __restrict__ Wf1, short* __restrict__ Wf2) {
    const int L1 = 12 * 4 * 2 * 512;  // 49152
    const int L2 = 12 * 2 * 2 * 512;  // 24576
    int tid = blockIdx.x * blockDim.x + threadIdx.x;
    if (tid < L1) {
        repack_one(W1, W1 + (size_t)IN_DIM * 64, root1, Wf1, 4, tid);
    } else if (tid < L1 + L2) {
        repack_one(W2, W2 + (size_t)HID * 64, root2, Wf2, 2, tid - L1);
    }
}

// ---------------------------------------------------------------------------
// Split-bf16 MFMA GEMM v3: LDS-staged W fragments, two K-phases.
// Block = 256 threads = 4 waves x 16 rows = 64 rows; every wave computes
// ALL 12 col-tiles (Wf L2 traffic amortized 4x vs R6). Per phase: stage
// 12*TH*2 KB of fragments into LDS cooperatively (reg staging, 1KB chunks
// contiguous in src and dst), barrier, then conflict-free ds_read_b128 +
// MFMA. K=128: TH=2, 48KB LDS (3 blocks/CU); K=64: TH=1, 24KB.
// X loaded fp32 up-front per wave, split to bf16 hi/lo once.
// ---------------------------------------------------------------------------
template <int K>
__global__ __launch_bounds__(256, 3) void gemm_mfma(
    const float* __restrict__ X, const short* __restrict__ Wf,
    float* __restrict__ PA, float* __restrict__ PB, float* __restrict__ PR,
    int M) {
    constexpr int T = K / 32;
    constexpr int TH = T / 2;                 // t-steps per phase (2 phases)
    __shared__ s16x8 WfL[12 * TH * 2 * 64];   // 48KB (K=128) / 24KB (K=64)

    const int tid = threadIdx.x;
    const int lane = tid & 63;
    const int wid = tid >> 6;
    const int row0 = blockIdx.x * 64 + wid * 16;

    int arow = row0 + (lane & 15);
    if (arow > M - 1) arow = M - 1;
    const float* xr = X + (size_t)arow * K + ((lane >> 4) << 3);
    const s16x8* WfV = (const s16x8*)Wf;

    // ---- all X loads up-front ----
    float4 xa[T][2];
#pragma unroll
    for (int t = 0; t < T; ++t) {
        xa[t][0] = *reinterpret_cast<const float4*>(xr + t * 32);
        xa[t][1] = *reinterpret_cast<const float4*>(xr + t * 32 + 4);
    }
    // ---- split once ----
    s16x8 ah[T], al[T];
#pragma unroll
    for (int t = 0; t < T; ++t) {
        const float av[8] = {xa[t][0].x, xa[t][0].y, xa[t][0].z, xa[t][0].w,
                             xa[t][1].x, xa[t][1].y, xa[t][1].z, xa[t][1].w};
#pragma unroll
        for (int j = 0; j < 8; ++j) {
            short h = f2bf(av[j]);
            ah[t][j] = h;
            al[t][j] = f2bf(av[j] - bf2f(h));
        }
    }

    f32x4 acc[12];
#pragma unroll
    for (int c = 0; c < 12; ++c) acc[c] = (f32x4){0.f, 0.f, 0.f, 0.f};

#pragma unroll
    for (int ph = 0; ph < 2; ++ph) {
        if (ph) __syncthreads();   // protect LDS reuse across phases
        // ---- stage this phase's fragments (1KB groups, linear copy) ----
#pragma unroll
        for (int it = 0; it < (12 * TH * 2 * 64) / 256; ++it) {
            const int v = it * 256 + tid;
            const int chunk = v >> 6;          // which 1KB group
            const int i = v & 63;              // 16B unit within group
            const int c = chunk / (TH * 2);
            const int rem = chunk - c * (TH * 2);
            const int tl = rem >> 1;
            const int part = rem & 1;
            const int gsrc = (c * T + ph * TH + tl) * 2 + part;
            WfL[v] = WfV[(size_t)gsrc * 64 + i];
        }
        __syncthreads();
        // ---- compute: 12 col-tiles x TH k-steps from LDS ----
#pragma unroll
        for (int c = 0; c < 12; ++c) {
#pragma unroll
            for (int tl = 0; tl < TH; ++tl) {
                const s16x8 bh = WfL[((c * TH + tl) * 2 + 0) * 64 + lane];
                const s16x8 bl = WfL[((c * TH + tl) * 2 + 1) * 64 + lane];
                const int tg = ph * TH + tl;
                acc[c] = __builtin_amdgcn_mfma_f32_16x16x32_bf16(ah[tg], bh,
                                                                 acc[c], 0, 0, 0);
                acc[c] = __builtin_amdgcn_mfma_f32_16x16x32_bf16(al[tg], bh,
                                                                 acc[c], 0, 0, 0);
                acc[c] = __builtin_amdgcn_mfma_f32_16x16x32_bf16(ah[tg], bl,
                                                                 acc[c], 0, 0, 0);
            }
        }
    }

    // ---- epilogue: D-frag col=lane&15, row=(lane>>4)*4+q ----
    const int drow = row0 + ((lane >> 4) << 2);
    const int dcol = lane & 15;
#pragma unroll
    for (int cg = 0; cg < 12; ++cg) {
        float* base = (cg < 4) ? PA : (cg < 8) ? PB : PR;
        const int cc = (cg & 3) * 16 + dcol;
#pragma unroll
        for (int q = 0; q < 4; ++q) {
            const int row = drow + q;
            if (row < M) base[(size_t)row * 64 + cc] = acc[cg][q];
        }
    }
}

// ---------------------------------------------------------------------------
// Aggregate + LayerNorm (+ optional exact GELU), fused single edge loop.
// (unchanged from R7)
// ---------------------------------------------------------------------------
__device__ __forceinline__ float4 shfl_xor_f4(float4 v, int m) {
    return make_float4(__shfl_xor(v.x, m), __shfl_xor(v.y, m),
                       __shfl_xor(v.z, m), __shfl_xor(v.w, m));
}

__global__ __launch_bounds__(256) void agg_ln_kernel(
    const float* __restrict__ Pcat,   // [2N,64] = PA|PB
    const float* __restrict__ PR,
    const int* __restrict__ rowptr,   // [N+1], dst-grouped
    const int2* __restrict__ colw,    // [E] {row, invdeg bits}
    const float* __restrict__ bias, const float* __restrict__ g,
    const float* __restrict__ beta,
    float* __restrict__ out, int N, int gelu) {
    const int t = threadIdx.x;
    const int lane = t & 63;
    const int sub = lane >> 4;
    const int c = lane & 15;
    const int node = blockIdx.x * 4 + (t >> 6);
    if (node >= N) return;

    const int c4 = c * 4;
    float4 acc = *reinterpret_cast<const float4*>(PR + (size_t)node * 64 + c4);
    {
        float4 b4 = *reinterpret_cast<const float4*>(bias + c4);
        acc.x += b4.x; acc.y += b4.y; acc.z += b4.z; acc.w += b4.w;
    }

    const int beg = rowptr[node];
    const int end = rowptr[node + 1];
    float4 s0 = make_float4(0.f, 0.f, 0.f, 0.f);
    float4 s1 = s0, s2 = s0, s3 = s0;
    for (int i = beg + sub; i < end; i += 16) {
        {
            const int2 w = colw[i];
            const float4 v = *reinterpret_cast<const float4*>(Pcat + w.x * 64 + c4);
            const float f = __int_as_float(w.y);
            s0.x = fmaf(v.x, f, s0.x); s0.y = fmaf(v.y, f, s0.y);
            s0.z = fmaf(v.z, f, s0.z); s0.w = fmaf(v.w, f, s0.w);
        }
        int j = i + 4;
        if (j < end) {
            const int2 w = colw[j];
            const float4 v = *reinterpret_cast<const float4*>(Pcat + w.x * 64 + c4);
            const float f = __int_as_float(w.y);
            s1.x = fmaf(v.x, f, s1.x); s1.y = fmaf(v.y, f, s1.y);
            s1.z = fmaf(v.z, f, s1.z); s1.w = fmaf(v.w, f, s1.w);
        }
        j = i + 8;
        if (j < end) {
            const int2 w = colw[j];
            const float4 v = *reinterpret_cast<const float4*>(Pcat + w.x * 64 + c4);
            const float f = __int_as_float(w.y);
            s2.x = fmaf(v.x, f, s2.x); s2.y = fmaf(v.y, f, s2.y);
            s2.z = fmaf(v.z, f, s2.z); s2.w = fmaf(v.w, f, s2.w);
        }
        j = i + 12;
        if (j < end) {
            const int2 w = colw[j];
            const float4 v = *reinterpret_cast<const float4*>(Pcat + w.x * 64 + c4);
            const float f = __int_as_float(w.y);
            s3.x = fmaf(v.x, f, s3.x); s3.y = fmaf(v.y, f, s3.y);
            s3.z = fmaf(v.z, f, s3.z); s3.w = fmaf(v.w, f, s3.w);
        }
    }
    s0.x += s1.x + s2.x + s3.x;
    s0.y += s1.y + s2.y + s3.y;
    s0.z += s1.z + s2.z + s3.z;
    s0.w += s1.w + s2.w + s3.w;
    float4 o = shfl_xor_f4(s0, 16);
    s0.x += o.x; s0.y += o.y; s0.z += o.z; s0.w += o.w;
    o = shfl_xor_f4(s0, 32);
    s0.x += o.x; s0.y += o.y; s0.z += o.z; s0.w += o.w;
    acc.x += s0.x; acc.y += s0.y; acc.z += s0.z; acc.w += s0.w;

    // LayerNorm over 64 features (16 lanes x float4; replicated x4 subs)
    float ps = acc.x + acc.y + acc.z + acc.w;
#pragma unroll
    for (int off = 1; off <= 8; off <<= 1) ps += __shfl_xor(ps, off);
    const float mu = ps * (1.f / 64.f);
    const float4 d = make_float4(acc.x - mu, acc.y - mu, acc.z - mu, acc.w - mu);
    float vs = d.x * d.x + d.y * d.y + d.z * d.z + d.w * d.w;
#pragma unroll
    for (int off = 1; off <= 8; off <<= 1) vs += __shfl_xor(vs, off);
    const float rstd = 1.f / sqrtf(vs * (1.f / 64.f) + 1e-5f);

    const float4 g4 = *reinterpret_cast<const float4*>(g + c4);
    const float4 be4 = *reinterpret_cast<const float4*>(beta + c4);
    float4 y;
    y.x = d.x * rstd * g4.x + be4.x;
    y.y = d.y * rstd * g4.y + be4.y;
    y.z = d.z * rstd * g4.z + be4.z;
    y.w = d.w * rstd * g4.w + be4.w;

    if (gelu) {
        y.x = 0.5f * y.x * (1.f + erff(y.x * 0.70710678118654752440f));
        y.y = 0.5f * y.y * (1.f + erff(y.y * 0.70710678118654752440f));
        y.z = 0.5f * y.z * (1.f + erff(y.z * 0.70710678118654752440f));
        y.w = 0.5f * y.w * (1.f + erff(y.w * 0.70710678118654752440f));
    }

    if (sub == 0)
        *reinterpret_cast<float4*>(out + (size_t)node * 64 + c4) = y;
}

// ---------------------------------------------------------------------------
// Launch
// ---------------------------------------------------------------------------
extern "C" void kernel_launch(void* const* d_in, const int* in_sizes, int n_in,
                              void* d_out, int out_size, void* d_ws, size_t ws_size,
                              hipStream_t stream) {
    const float* x = (const float*)d_in[0];
    const int* ei = (const int*)d_in[1];   // [2][E]: src row then dst row
    const int* et = (const int*)d_in[2];   // [E]
    const float* W1 = (const float*)d_in[3];    // [2][128][64]
    const float* root1 = (const float*)d_in[4]; // [128][64]
    const float* b1 = (const float*)d_in[5];
    const float* g1 = (const float*)d_in[6];
    const float* beta1 = (const float*)d_in[7];
    const float* W2 = (const float*)d_in[8];    // [2][64][64]
    const float* root2 = (const float*)d_in[9]; // [64][64]
    const float* b2 = (const float*)d_in[10];
    const float* g2 = (const float*)d_in[11];
    const float* beta2 = (const float*)d_in[12];

    const int E = in_sizes[2];
    const int N = in_sizes[0] / IN_DIM;

    const int WF1 = 12 * 4 * 2 * 512;  // 49152 shorts
    const int WF2 = 12 * 2 * 2 * 512;  // 24576 shorts

    // workspace layout: Wf packs, float bufs, colw (8B-aligned), int bufs
    short* Wf1 = (short*)d_ws;
    short* Wf2 = Wf1 + WF1;
    float* Pcat = (float*)(Wf2 + WF2);           // [2N,64] = PA|PB
    float* PR   = Pcat + (size_t)2 * N * 64;
    float* H    = PR + (size_t)N * 64;
    int2* colw  = (int2*)(H + (size_t)N * 64);   // E entries, 8B aligned
    int* cnt2   = (int*)(colw + E);              // 2N
    int* excl   = cnt2 + 2 * N;                  // N
    int* rowptr = excl + N;                      // N+1
    int* cursor = rowptr + N + 1;                // N
    int* bsum   = cursor + N;                    // 256
    int* boff   = bsum + 256;                    // 256

    const int* esrc = ei;
    const int* edst = ei + E;

    // ---- CSR build (dst-grouped, per-rel counts for inv-deg) ----
    zero_ints<<<(2 * N + 255) / 256, 256, 0, stream>>>(cnt2, 2 * N);
    count_edges<<<(E + 255) / 256, 256, 0, stream>>>(et, edst, cnt2, E, N);
    int nb = (N + SCAN_T * SCAN_I - 1) / (SCAN_T * SCAN_I);
    scan_phase1<<<nb, SCAN_T, 0, stream>>>(cnt2, cnt2 + N, excl, bsum, N);
    scan_phase1<<<1, SCAN_T, 0, stream>>>(bsum, nullptr, boff, nullptr, nb);
    scan_phase3<<<(N + 255) / 256, 256, 0, stream>>>(excl, boff, rowptr, cursor, N, E);
    fill_edges<<<(E + 255) / 256, 256, 0, stream>>>(et, esrc, edst, cnt2, cursor,
                                                    colw, E, N);

    // ---- W repack (both layers, fragment order, hi/lo split) ----
    repack_w_frag<<<(WF1 + WF2 + 255) / 256, 256, 0, stream>>>(
        W1, root1, W2, root2, Wf1, Wf2);

    // ---- Layer 1 ----
    int gblocks = (N + 63) / 64;
    gemm_mfma<IN_DIM><<<gblocks, 256, 0, stream>>>(
        x, Wf1, Pcat, Pcat + (size_t)N * 64, PR, N);
    agg_ln_kernel<<<(N + 3) / 4, 256, 0, stream>>>(Pcat, PR, rowptr, colw, b1, g1,
                                                   beta1, H, N, 1);

    // ---- Layer 2 ----
    gemm_mfma<HID><<<gblocks, 256, 0, stream>>>(
        H, Wf2, Pcat, Pcat + (size_t)N * 64, PR, N);
    agg_ln_kernel<<<(N + 3) / 4, 256, 0, stream>>>(Pcat, PR, rowptr, colw, b2, g2,
                                                   beta2, (float*)d_out, N, 0);
}